// Round 8
// baseline (644.884 us; speedup 1.0000x reference)
//
#include <hip/hip_runtime.h>
#include <cmath>

#define SEQ 2048
#define DDIM 1024
#define NROWS 8192   // B*S
#define KSEL 8
#define IMAXC 0x7fffffff

typedef __attribute__((ext_vector_type(8))) short bf16x8;
typedef __attribute__((ext_vector_type(4))) float f32x4;
typedef __attribute__((ext_vector_type(4))) double f64x4;

__device__ __forceinline__ unsigned short f2bf(float f) {
  unsigned u = __builtin_bit_cast(unsigned, f);
  u = (u + 0x7fffu + ((u >> 16) & 1u)) >> 16;
  return (unsigned short)u;
}
__device__ __forceinline__ float bf2f(unsigned short h) {
  unsigned u = ((unsigned)h) << 16;
  return __builtin_bit_cast(float, u);
}
__device__ __forceinline__ unsigned pkbf(float a, float b) {
  unsigned r;
  asm("v_cvt_pk_bf16_f32 %0, %1, %2" : "=v"(r) : "v"(a), "v"(b));
  return r;
}
// D-fragment (row,col) within a 16x16 tile for f64 mfma, by probed layout sel
__device__ __forceinline__ void dmap(int sel, int lg, int lr, int rg,
                                     int& ri, int& ci) {
  switch (sel) {
    case 0:  ri = (lg << 2) + rg; ci = lr; break;
    case 1:  ri = lg + (rg << 2); ci = lr; break;
    case 2:  ri = lr; ci = (lg << 2) + rg; break;
    default: ri = lr; ci = lg + (rg << 2); break;
  }
}

// ---------------------------------------------------------------------------
// kprobe: one wave determines the f64-MFMA D layout among 4 candidates using
// exact integer-valued f64 inputs (order-independent => bitwise equality).
// sel=4 means unknown -> vector repair kernels take over. -- UNCHANGED
// ---------------------------------------------------------------------------
__global__ void kprobe(int* __restrict__ sel) {
  const int lane = threadIdx.x;
  const int lr = lane & 15, lg = lane >> 4;
  const double a = (double)(4 * lr + lg + 1);       // A[r=lr][k=lg]
  const double b = (double)(9 * lr + 5 * lg + 2);   // B[c=lr][k=lg] (asym)
  f64x4 d = (f64x4){0.0, 0.0, 0.0, 0.0};
  d = __builtin_amdgcn_mfma_f64_16x16x4f64(a, b, d, 0, 0, 0);
  int my = 4;
  for (int s = 3; s >= 0; --s) {
    bool ok = true;
    for (int rg = 0; rg < 4; ++rg) {
      int ri, ci;
      dmap(s, lg, lr, rg, ri, ci);
      double e = 0.0;
      for (int k = 0; k < 4; ++k)
        e += (double)(4 * ri + k + 1) * (double)(9 * ci + 5 * k + 2);
      ok = ok && (d[rg] == e);
    }
    if (__all(ok)) my = s;
  }
  if (lane == 0) sel[0] = my;
}

// ---------------------------------------------------------------------------
// k0_mfma: Wc = Wphi^T * Wpsi (TN, f64 MFMA). -- UNCHANGED
// ---------------------------------------------------------------------------
__global__ __launch_bounds__(256, 2)
void k0_mfma(const float* __restrict__ A, const float* __restrict__ B,
             float* __restrict__ C, const int* __restrict__ selp) {
  const int sel = selp[0];
  if (sel >= 4) return;
  __shared__ float As[32][72];
  __shared__ float Bs[32][72];
  const int tid = threadIdx.x;
  const int lane = tid & 63, w = tid >> 6;
  const int wr = w >> 1, wc = w & 1;
  const int lr = lane & 15, lg = lane >> 4;
  const int brow = blockIdx.y << 6, bcol = blockIdx.x << 6;
  const int kr = tid >> 3, c4 = (tid & 7) << 2;

  f64x4 acc[2][2];
#pragma unroll
  for (int mi = 0; mi < 2; ++mi)
#pragma unroll
    for (int nj = 0; nj < 2; ++nj)
      acc[mi][nj] = (f64x4){0.0, 0.0, 0.0, 0.0};

  const float* Ap = &A[(size_t)kr * DDIM + brow + c4];
  const float* Bp = &B[(size_t)kr * DDIM + bcol + c4];
  float4 pa0 = *reinterpret_cast<const float4*>(Ap);
  float4 pa1 = *reinterpret_cast<const float4*>(Ap + 32);
  float4 pb0 = *reinterpret_cast<const float4*>(Bp);
  float4 pb1 = *reinterpret_cast<const float4*>(Bp + 32);

  for (int k0 = 0; k0 < DDIM; k0 += 32) {
    __syncthreads();
    *reinterpret_cast<float4*>(&As[kr][c4]) = pa0;
    *reinterpret_cast<float4*>(&As[kr][c4 + 32]) = pa1;
    *reinterpret_cast<float4*>(&Bs[kr][c4]) = pb0;
    *reinterpret_cast<float4*>(&Bs[kr][c4 + 32]) = pb1;
    __syncthreads();
    if (k0 + 32 < DDIM) {
      const size_t nk = (size_t)(k0 + 32) * DDIM;
      pa0 = *reinterpret_cast<const float4*>(Ap + nk);
      pa1 = *reinterpret_cast<const float4*>(Ap + nk + 32);
      pb0 = *reinterpret_cast<const float4*>(Bp + nk);
      pb1 = *reinterpret_cast<const float4*>(Bp + nk + 32);
    }
#pragma unroll
    for (int kp = 0; kp < 8; ++kp) {
      const int ka = (kp << 2) + lg;
      double a[2], b[2];
#pragma unroll
      for (int mi = 0; mi < 2; ++mi)
        a[mi] = (double)As[ka][(wr << 5) + (mi << 4) + lr];
#pragma unroll
      for (int nj = 0; nj < 2; ++nj)
        b[nj] = (double)Bs[ka][(wc << 5) + (nj << 4) + lr];
#pragma unroll
      for (int mi = 0; mi < 2; ++mi)
#pragma unroll
        for (int nj = 0; nj < 2; ++nj)
          acc[mi][nj] = __builtin_amdgcn_mfma_f64_16x16x4f64(
              a[mi], b[nj], acc[mi][nj], 0, 0, 0);
    }
  }
#pragma unroll
  for (int mi = 0; mi < 2; ++mi)
#pragma unroll
    for (int nj = 0; nj < 2; ++nj)
#pragma unroll
      for (int rg = 0; rg < 4; ++rg) {
        int ri, ci;
        dmap(sel, lg, lr, rg, ri, ci);
        C[(size_t)(brow + (wr << 5) + (mi << 4) + ri) * DDIM +
          bcol + (wc << 5) + (nj << 4) + ci] = (float)acc[mi][nj][rg];
      }
}

// ---------------------------------------------------------------------------
// k0_repair: proven vector-f64 TN kernel; runs only if sel unknown. -- UNCHANGED
// ---------------------------------------------------------------------------
__global__ __launch_bounds__(256)
void k0_repair(const float* __restrict__ A, const float* __restrict__ B,
               float* __restrict__ C, const int* __restrict__ selp) {
  if (selp[0] < 4) return;
  __shared__ __align__(16) float As[32][68];
  __shared__ __align__(16) float Bs[32][68];
  const int tid = threadIdx.x;
  const int tx = tid & 15, ty = tid >> 4;
  const int brow = blockIdx.y << 6;
  const int bcol = blockIdx.x << 6;
  double acc[4][4] = {};
  for (int k0 = 0; k0 < DDIM; k0 += 32) {
#pragma unroll
    for (int i = 0; i < 2; ++i) {
      const int f = tid + (i << 8);
      const int r = f >> 4;
      const int c4 = (f & 15) << 2;
      *reinterpret_cast<float4*>(&As[r][c4]) =
          *reinterpret_cast<const float4*>(&A[(size_t)(k0 + r) * DDIM + brow + c4]);
      *reinterpret_cast<float4*>(&Bs[r][c4]) =
          *reinterpret_cast<const float4*>(&B[(size_t)(k0 + r) * DDIM + bcol + c4]);
    }
    __syncthreads();
#pragma unroll
    for (int kk = 0; kk < 32; ++kk) {
      const float4 a = *reinterpret_cast<const float4*>(&As[kk][ty << 2]);
      const float4 b = *reinterpret_cast<const float4*>(&Bs[kk][tx << 2]);
      const double ad[4] = {a.x, a.y, a.z, a.w};
      const double bd[4] = {b.x, b.y, b.z, b.w};
#pragma unroll
      for (int i = 0; i < 4; ++i)
#pragma unroll
        for (int j = 0; j < 4; ++j)
          acc[i][j] = fma(ad[i], bd[j], acc[i][j]);
    }
    __syncthreads();
  }
#pragma unroll
  for (int i = 0; i < 4; ++i) {
    float4 v = make_float4((float)acc[i][0], (float)acc[i][1],
                           (float)acc[i][2], (float)acc[i][3]);
    *reinterpret_cast<float4*>(
        &C[(size_t)(brow + (ty << 2) + i) * DDIM + bcol + (tx << 2)]) = v;
  }
}

// ---------------------------------------------------------------------------
// k1_mfma: T = H * Wc (NN, f64 MFMA), dbuf, 1 barrier/K-step. -- UNCHANGED
// ---------------------------------------------------------------------------
#define K1_STAGE(bi)                                              \
  do {                                                            \
    As[bi][akh + 0][ar] = pa0.x; As[bi][akh + 1][ar] = pa0.y;     \
    As[bi][akh + 2][ar] = pa0.z; As[bi][akh + 3][ar] = pa0.w;     \
    As[bi][akh + 4][ar] = pa1.x; As[bi][akh + 5][ar] = pa1.y;     \
    As[bi][akh + 6][ar] = pa1.z; As[bi][akh + 7][ar] = pa1.w;     \
    *reinterpret_cast<float4*>(&Bs[bi][bk][bc4]) = pb0;           \
    *reinterpret_cast<float4*>(&Bs[bi][bk][bc4 + 64]) = pb1;      \
  } while (0)

__global__ __launch_bounds__(256, 2)
void k1_mfma(const float* __restrict__ A, const float* __restrict__ B,
             float* __restrict__ C, const int* __restrict__ selp) {
  const int sel = selp[0];
  if (sel >= 4) return;
  __shared__ float As[2][16][144];
  __shared__ float Bs[2][16][144];
  const int tid = threadIdx.x;
  const int lin = blockIdx.y * 8 + blockIdx.x;          // 512 blocks
  const int nlin = (lin & 7) * 64 + (lin >> 3);         // bijective XCD swizzle
  const int brow = (nlin >> 3) << 7;
  const int bcol = (nlin & 7) << 7;
  const int lane = tid & 63, w = tid >> 6;
  const int wr = w >> 1, wc = w & 1;
  const int lr = lane & 15, lg = lane >> 4;
  const int ar = tid >> 1, akh = (tid & 1) << 3;
  const int bk = tid >> 4, bc4 = (tid & 15) << 2;

  f64x4 acc[4][4];
#pragma unroll
  for (int mi = 0; mi < 4; ++mi)
#pragma unroll
    for (int nj = 0; nj < 4; ++nj)
      acc[mi][nj] = (f64x4){0.0, 0.0, 0.0, 0.0};

  const float* Ap = &A[(size_t)(brow + ar) * DDIM + akh];
  const float* Bp = &B[(size_t)bk * DDIM + bcol + bc4];

  float4 pa0 = *reinterpret_cast<const float4*>(Ap);
  float4 pa1 = *reinterpret_cast<const float4*>(Ap + 4);
  float4 pb0 = *reinterpret_cast<const float4*>(Bp);
  float4 pb1 = *reinterpret_cast<const float4*>(Bp + 64);
  K1_STAGE(0);
  pa0 = *reinterpret_cast<const float4*>(Ap + 16);
  pa1 = *reinterpret_cast<const float4*>(Ap + 20);
  pb0 = *reinterpret_cast<const float4*>(Bp + (size_t)16 * DDIM);
  pb1 = *reinterpret_cast<const float4*>(Bp + (size_t)16 * DDIM + 64);

  for (int t = 0; t < 64; ++t) {
    __syncthreads();
    const int cur = t & 1;
    if (t < 63) {
      K1_STAGE(cur ^ 1);
      if (t < 62) {
        const size_t ko = (size_t)(t + 2) << 4;
        pa0 = *reinterpret_cast<const float4*>(Ap + ko);
        pa1 = *reinterpret_cast<const float4*>(Ap + ko + 4);
        pb0 = *reinterpret_cast<const float4*>(Bp + ko * DDIM);
        pb1 = *reinterpret_cast<const float4*>(Bp + ko * DDIM + 64);
      }
    }
#pragma unroll
    for (int kp = 0; kp < 4; ++kp) {
      const int ka = (kp << 2) + lg;
      double a[4], b[4];
#pragma unroll
      for (int mi = 0; mi < 4; ++mi)
        a[mi] = (double)As[cur][ka][(wr << 6) + (mi << 4) + lr];
#pragma unroll
      for (int nj = 0; nj < 4; ++nj)
        b[nj] = (double)Bs[cur][ka][(wc << 6) + (nj << 4) + lr];
#pragma unroll
      for (int mi = 0; mi < 4; ++mi)
#pragma unroll
        for (int nj = 0; nj < 4; ++nj)
          acc[mi][nj] = __builtin_amdgcn_mfma_f64_16x16x4f64(
              a[mi], b[nj], acc[mi][nj], 0, 0, 0);
    }
  }
#pragma unroll
  for (int mi = 0; mi < 4; ++mi)
#pragma unroll
    for (int nj = 0; nj < 4; ++nj)
#pragma unroll
      for (int rg = 0; rg < 4; ++rg) {
        int ri, ci;
        dmap(sel, lg, lr, rg, ri, ci);
        C[(size_t)(brow + (wr << 6) + (mi << 4) + ri) * DDIM +
          bcol + (wc << 6) + (nj << 4) + ci] = (float)acc[mi][nj][rg];
      }
}

// ---------------------------------------------------------------------------
// k1_repair: proven vector-f64 chain kernel; runs only if sel unknown. -- UNCHANGED
// ---------------------------------------------------------------------------
__global__ __launch_bounds__(256, 2)
void k1_repair(const float* __restrict__ A, const float* __restrict__ B,
               float* __restrict__ C, const int* __restrict__ selp) {
  if (selp[0] < 4) return;
  __shared__ double As[128][17];
  __shared__ double Bs[16][130];
  const int tid = threadIdx.x;
  const int lin = blockIdx.y * 8 + blockIdx.x;
  const int nlin = (lin & 7) * 64 + (lin >> 3);
  const int brow = (nlin >> 3) << 7;
  const int bcol = (nlin & 7) << 7;
  const int tx = tid & 15, ty = tid >> 4;
  const int ar = tid >> 1, aks = (tid & 1) << 3;
  const int bk = tid >> 4, btx = tid & 15;

  double acc[8][8];
#pragma unroll
  for (int i = 0; i < 8; ++i)
#pragma unroll
    for (int j = 0; j < 8; ++j) acc[i][j] = 0.0;

  const float* Aptr = &A[(size_t)(brow + ar) * DDIM + aks];
  const float* Bptr = &B[(size_t)bk * DDIM + bcol + (btx << 1)];

  float4 pa0, pa1;
  float2 pb[4];
  pa0 = *reinterpret_cast<const float4*>(Aptr);
  pa1 = *reinterpret_cast<const float4*>(Aptr + 4);
#pragma unroll
  for (int w = 0; w < 4; ++w)
    pb[w] = *reinterpret_cast<const float2*>(Bptr + (w << 5));

  for (int k0 = 0; k0 < DDIM; k0 += 16) {
    __syncthreads();
    As[ar][aks + 0] = (double)pa0.x; As[ar][aks + 1] = (double)pa0.y;
    As[ar][aks + 2] = (double)pa0.z; As[ar][aks + 3] = (double)pa0.w;
    As[ar][aks + 4] = (double)pa1.x; As[ar][aks + 5] = (double)pa1.y;
    As[ar][aks + 6] = (double)pa1.z; As[ar][aks + 7] = (double)pa1.w;
#pragma unroll
    for (int w = 0; w < 4; ++w) {
      Bs[bk][(btx << 1) + (w << 5) + 0] = (double)pb[w].x;
      Bs[bk][(btx << 1) + (w << 5) + 1] = (double)pb[w].y;
    }
    __syncthreads();
    if (k0 + 16 < DDIM) {
      pa0 = *reinterpret_cast<const float4*>(Aptr + k0 + 16);
      pa1 = *reinterpret_cast<const float4*>(Aptr + k0 + 20);
#pragma unroll
      for (int w = 0; w < 4; ++w)
        pb[w] = *reinterpret_cast<const float2*>(
            Bptr + (size_t)(k0 + 16) * DDIM + (w << 5));
    }
#pragma unroll 8
    for (int kk = 0; kk < 16; ++kk) {
      double a[8];
      double2 b[4];
#pragma unroll
      for (int i = 0; i < 8; ++i) a[i] = As[(ty << 3) + i][kk];
#pragma unroll
      for (int jj = 0; jj < 4; ++jj)
        b[jj] = *reinterpret_cast<const double2*>(&Bs[kk][(tx << 1) + (jj << 5)]);
#pragma unroll
      for (int i = 0; i < 8; ++i) {
#pragma unroll
        for (int jj = 0; jj < 4; ++jj) {
          acc[i][(jj << 1) + 0] = fma(a[i], b[jj].x, acc[i][(jj << 1) + 0]);
          acc[i][(jj << 1) + 1] = fma(a[i], b[jj].y, acc[i][(jj << 1) + 1]);
        }
      }
    }
  }
#pragma unroll
  for (int i = 0; i < 8; ++i) {
    float* crow = &C[(size_t)(brow + (ty << 3) + i) * DDIM + bcol + (tx << 1)];
#pragma unroll
    for (int jj = 0; jj < 4; ++jj) {
      float2 v = make_float2((float)acc[i][(jj << 1)],
                             (float)acc[i][(jj << 1) + 1]);
      *reinterpret_cast<float2*>(crow + (jj << 5)) = v;
    }
  }
}

// ---------------------------------------------------------------------------
// kcvt2: T,H (f32) -> Tb,Hb (bf16 RNE). 8 elems of each per thread.
// ---------------------------------------------------------------------------
__global__ __launch_bounds__(256)
void kcvt2(const float* __restrict__ Tin, const float* __restrict__ Hin,
           unsigned short* __restrict__ Tb, unsigned short* __restrict__ Hb) {
  const size_t i = ((size_t)blockIdx.x * 256 + threadIdx.x) << 3;
  {
    const float4 a0 = *reinterpret_cast<const float4*>(&Tin[i]);
    const float4 a1 = *reinterpret_cast<const float4*>(&Tin[i + 4]);
    uint4 o;
    o.x = pkbf(a0.x, a0.y); o.y = pkbf(a0.z, a0.w);
    o.z = pkbf(a1.x, a1.y); o.w = pkbf(a1.z, a1.w);
    *reinterpret_cast<uint4*>(&Tb[i]) = o;
  }
  {
    const float4 a0 = *reinterpret_cast<const float4*>(&Hin[i]);
    const float4 a1 = *reinterpret_cast<const float4*>(&Hin[i + 4]);
    uint4 o;
    o.x = pkbf(a0.x, a0.y); o.y = pkbf(a0.z, a0.w);
    o.z = pkbf(a1.x, a1.y); o.w = pkbf(a1.z, a1.w);
    *reinterpret_cast<uint4*>(&Hb[i]) = o;
  }
}

// ---------------------------------------------------------------------------
// k2_mfma_bf: approx scores from pre-converted bf16 Tb/Hb. Staging = raw
// uint4 copies (no cvt), chunked XCD swizzle (1024 = 8 x 128 bijective).
// Epilogue identical to k2_mfma.
// ---------------------------------------------------------------------------
__global__ __launch_bounds__(256)
void k2_mfma_bf(const unsigned short* __restrict__ Tb,
                const unsigned short* __restrict__ Hb,
                unsigned short* __restrict__ cand_v,
                unsigned char* __restrict__ cand_i) {
  __shared__ union {
    unsigned short stage[2][128 * 64];
    float Sl[64][130];
    struct {
      float mv[256][8];
      unsigned char mi[256][8];
    } mg;
  } u;
  const int tid = threadIdx.x;
  const int lane = tid & 63;
  const int w = tid >> 6;
  const int wr = w >> 1, wc = w & 1;
  const int lr = lane & 15, lg = lane >> 4;
  // chunked XCD swizzle: XCD gets 128 consecutive original blocks
  const int lin = blockIdx.z * 256 + blockIdx.y * 16 + blockIdx.x;
  const int nl = (lin & 7) * 128 + (lin >> 3);
  const int bx = nl & 15;
  const int by = (nl >> 4) & 15;
  const int bz = nl >> 8;
  const int brow = by << 7, bcol = bx << 7;
  const int row0g = bz * SEQ + brow;
  const int col0g = bz * SEQ + bcol;

  f32x4 acc[4][4];
#pragma unroll
  for (int mi = 0; mi < 4; ++mi)
#pragma unroll
    for (int nj = 0; nj < 4; ++nj)
      acc[mi][nj] = (f32x4){0.f, 0.f, 0.f, 0.f};

  for (int k0 = 0; k0 < DDIM; k0 += 64) {
    __syncthreads();
#pragma unroll
    for (int q = 0; q < 4; ++q) {
      const int c = (q << 8) + tid;
      const int row = c >> 3, slot = c & 7;
      const int gs = slot ^ (row & 7);
      *reinterpret_cast<uint4*>(&u.stage[0][c << 3]) =
          *reinterpret_cast<const uint4*>(
              &Tb[(size_t)(row0g + row) * DDIM + k0 + (gs << 3)]);
      *reinterpret_cast<uint4*>(&u.stage[1][c << 3]) =
          *reinterpret_cast<const uint4*>(
              &Hb[(size_t)(col0g + row) * DDIM + k0 + (gs << 3)]);
    }
    __syncthreads();
#pragma unroll
    for (int kh = 0; kh < 2; ++kh) {
      bf16x8 af[4], bf[4];
      const int sl = (kh << 2) + lg;
#pragma unroll
      for (int mi = 0; mi < 4; ++mi) {
        const int ra = (wr << 6) + (mi << 4) + lr;
        af[mi] = *reinterpret_cast<const bf16x8*>(
            &u.stage[0][(ra << 6) + ((sl ^ (ra & 7)) << 3)]);
        const int rb = (wc << 6) + (mi << 4) + lr;
        bf[mi] = *reinterpret_cast<const bf16x8*>(
            &u.stage[1][(rb << 6) + ((sl ^ (rb & 7)) << 3)]);
      }
#pragma unroll
      for (int mi = 0; mi < 4; ++mi)
#pragma unroll
        for (int nj = 0; nj < 4; ++nj)
          acc[mi][nj] = __builtin_amdgcn_mfma_f32_16x16x32_bf16(
              af[mi], bf[nj], acc[mi][nj], 0, 0, 0);
    }
  }

  const int srow = tid >> 2;
  const int qd = tid & 3;
  for (int p = 0; p < 2; ++p) {
    __syncthreads();
    if (wr == p) {
#pragma unroll
      for (int mi = 0; mi < 4; ++mi)
#pragma unroll
        for (int nj = 0; nj < 4; ++nj)
#pragma unroll
          for (int r = 0; r < 4; ++r)
            u.Sl[(mi << 4) + (lg << 2) + r][(wc << 6) + (nj << 4) + lr] =
                acc[mi][nj][r];
    }
    __syncthreads();
    float v[KSEL];
    int ci[KSEL];
#pragma unroll
    for (int s = 0; s < KSEL; ++s) { v[s] = -3.0e38f; ci[s] = 0; }
    const int c0 = qd << 5;
    for (int c = 0; c < 32; ++c) {
      const float x = u.Sl[srow][c0 + c];
      if (x > v[KSEL - 1]) {
        float pv = x; int pc = c0 + c;
#pragma unroll
        for (int s = 0; s < KSEL; ++s) {
          if (x > v[s]) {
            const float tv = v[s]; const int tc = ci[s];
            v[s] = pv; ci[s] = pc; pv = tv; pc = tc;
          }
        }
      }
    }
    __syncthreads();
#pragma unroll
    for (int s = 0; s < KSEL; ++s) {
      u.mg.mv[tid][s] = v[s];
      u.mg.mi[tid][s] = (unsigned char)ci[s];
    }
    __syncthreads();
    if (qd == 0) {
      float fv[KSEL];
      int fi[KSEL];
#pragma unroll
      for (int s = 0; s < KSEL; ++s) { fv[s] = -3.0e38f; fi[s] = 0; }
#pragma unroll
      for (int t = 0; t < 4; ++t) {
#pragma unroll
        for (int s = 0; s < KSEL; ++s) {
          const float x = u.mg.mv[tid + t][s];
          const int idx = u.mg.mi[tid + t][s];
          if (x > fv[KSEL - 1]) {
            float pv = x; int pc = idx;
#pragma unroll
            for (int s2 = 0; s2 < KSEL; ++s2) {
              if (x > fv[s2]) {
                const float tv = fv[s2]; const int tc = fi[s2];
                fv[s2] = pv; fi[s2] = pc; pv = tv; pc = tc;
              }
            }
          }
        }
      }
      const size_t base =
          (size_t)(row0g + (p << 6) + srow) * 128 + ((size_t)bx << 3);
#pragma unroll
      for (int s = 0; s < KSEL; ++s) {
        cand_v[base + s] = f2bf(fv[s]);
        cand_i[base + s] = (unsigned char)fi[s];
      }
    }
  }
}

// ---------------------------------------------------------------------------
// k2_mfma: f32-input fallback (pkbf in staging). -- UNCHANGED from R7
// ---------------------------------------------------------------------------
__global__ __launch_bounds__(256)
void k2_mfma(const float* __restrict__ T, const float* __restrict__ H,
             unsigned short* __restrict__ cand_v,
             unsigned char* __restrict__ cand_i) {
  __shared__ union {
    unsigned short stage[2][128 * 64];
    float Sl[64][130];
    struct {
      float mv[256][8];
      unsigned char mi[256][8];
    } mg;
  } u;
  const int tid = threadIdx.x;
  const int lane = tid & 63;
  const int w = tid >> 6;
  const int wr = w >> 1, wc = w & 1;
  const int lr = lane & 15, lg = lane >> 4;
  const int z = blockIdx.z;
  const int brow = blockIdx.y << 7, bcol = blockIdx.x << 7;
  const int row0g = z * SEQ + brow;
  const int col0g = z * SEQ + bcol;

  f32x4 acc[4][4];
#pragma unroll
  for (int mi = 0; mi < 4; ++mi)
#pragma unroll
    for (int nj = 0; nj < 4; ++nj)
      acc[mi][nj] = (f32x4){0.f, 0.f, 0.f, 0.f};

  for (int k0 = 0; k0 < DDIM; k0 += 64) {
    __syncthreads();
#pragma unroll
    for (int q = 0; q < 4; ++q) {
      const int c = (q << 8) + tid;
      const int row = c >> 3, slot = c & 7;
      const int gs = slot ^ (row & 7);
      {
        const float* s = &T[(size_t)(row0g + row) * DDIM + k0 + (gs << 3)];
        const float4 f0 = *reinterpret_cast<const float4*>(s);
        const float4 f1 = *reinterpret_cast<const float4*>(s + 4);
        uint4 o;
        o.x = pkbf(f0.x, f0.y); o.y = pkbf(f0.z, f0.w);
        o.z = pkbf(f1.x, f1.y); o.w = pkbf(f1.z, f1.w);
        *reinterpret_cast<uint4*>(&u.stage[0][c << 3]) = o;
      }
      {
        const float* s = &H[(size_t)(col0g + row) * DDIM + k0 + (gs << 3)];
        const float4 f0 = *reinterpret_cast<const float4*>(s);
        const float4 f1 = *reinterpret_cast<const float4*>(s + 4);
        uint4 o;
        o.x = pkbf(f0.x, f0.y); o.y = pkbf(f0.z, f0.w);
        o.z = pkbf(f1.x, f1.y); o.w = pkbf(f1.z, f1.w);
        *reinterpret_cast<uint4*>(&u.stage[1][c << 3]) = o;
      }
    }
    __syncthreads();
#pragma unroll
    for (int kh = 0; kh < 2; ++kh) {
      bf16x8 af[4], bf[4];
      const int sl = (kh << 2) + lg;
#pragma unroll
      for (int mi = 0; mi < 4; ++mi) {
        const int ra = (wr << 6) + (mi << 4) + lr;
        af[mi] = *reinterpret_cast<const bf16x8*>(
            &u.stage[0][(ra << 6) + ((sl ^ (ra & 7)) << 3)]);
        const int rb = (wc << 6) + (mi << 4) + lr;
        bf[mi] = *reinterpret_cast<const bf16x8*>(
            &u.stage[1][(rb << 6) + ((sl ^ (rb & 7)) << 3)]);
      }
#pragma unroll
      for (int mi = 0; mi < 4; ++mi)
#pragma unroll
        for (int nj = 0; nj < 4; ++nj)
          acc[mi][nj] = __builtin_amdgcn_mfma_f32_16x16x32_bf16(
              af[mi], bf[nj], acc[mi][nj], 0, 0, 0);
    }
  }

  const int bx = blockIdx.x;
  const int srow = tid >> 2;
  const int qd = tid & 3;
  for (int p = 0; p < 2; ++p) {
    __syncthreads();
    if (wr == p) {
#pragma unroll
      for (int mi = 0; mi < 4; ++mi)
#pragma unroll
        for (int nj = 0; nj < 4; ++nj)
#pragma unroll
          for (int r = 0; r < 4; ++r)
            u.Sl[(mi << 4) + (lg << 2) + r][(wc << 6) + (nj << 4) + lr] =
                acc[mi][nj][r];
    }
    __syncthreads();
    float v[KSEL];
    int ci[KSEL];
#pragma unroll
    for (int s = 0; s < KSEL; ++s) { v[s] = -3.0e38f; ci[s] = 0; }
    const int c0 = qd << 5;
    for (int c = 0; c < 32; ++c) {
      const float x = u.Sl[srow][c0 + c];
      if (x > v[KSEL - 1]) {
        float pv = x; int pc = c0 + c;
#pragma unroll
        for (int s = 0; s < KSEL; ++s) {
          if (x > v[s]) {
            const float tv = v[s]; const int tc = ci[s];
            v[s] = pv; ci[s] = pc; pv = tv; pc = tc;
          }
        }
      }
    }
    __syncthreads();
#pragma unroll
    for (int s = 0; s < KSEL; ++s) {
      u.mg.mv[tid][s] = v[s];
      u.mg.mi[tid][s] = (unsigned char)ci[s];
    }
    __syncthreads();
    if (qd == 0) {
      float fv[KSEL];
      int fi[KSEL];
#pragma unroll
      for (int s = 0; s < KSEL; ++s) { fv[s] = -3.0e38f; fi[s] = 0; }
#pragma unroll
      for (int t = 0; t < 4; ++t) {
#pragma unroll
        for (int s = 0; s < KSEL; ++s) {
          const float x = u.mg.mv[tid + t][s];
          const int idx = u.mg.mi[tid + t][s];
          if (x > fv[KSEL - 1]) {
            float pv = x; int pc = idx;
#pragma unroll
            for (int s2 = 0; s2 < KSEL; ++s2) {
              if (x > fv[s2]) {
                const float tv = fv[s2]; const int tc = fi[s2];
                fv[s2] = pv; fi[s2] = pc; pv = tv; pc = tc;
              }
            }
          }
        }
      }
      const size_t base =
          (size_t)(row0g + (p << 6) + srow) * 128 + ((size_t)bx << 3);
#pragma unroll
      for (int s = 0; s < KSEL; ++s) {
        cand_v[base + s] = f2bf(fv[s]);
        cand_i[base + s] = (unsigned char)fi[s];
      }
    }
  }
}

// ---------------------------------------------------------------------------
// kr_rescore: extraction (unchanged) + PARALLEL exact f64 rescore:
// 16 groups x 4 lanes compute all 16 candidate dots concurrently, 2-step
// shfl reduce, then stable (aff desc, idx asc) top-8.
// ---------------------------------------------------------------------------
__global__ __launch_bounds__(256)
void kr_rescore(const float* __restrict__ T, const float* __restrict__ H,
                const unsigned short* __restrict__ cand_v,
                const unsigned char* __restrict__ cand_i,
                int* __restrict__ topi, float* __restrict__ topw,
                int* __restrict__ cnt) {
  const int tid = threadIdx.x, lane = tid & 63, w = tid >> 6;
  const int r = blockIdx.x * 4 + w;
  const int b = r >> 11, iloc = r & (SEQ - 1);

  // --- extraction of approx-top-16 (identical math to R7) ---
  const size_t cbase = (size_t)r * 128;
  const int s0 = lane << 1, s1 = s0 + 1;
  float v0 = bf2f(cand_v[cbase + s0]);
  float v1 = bf2f(cand_v[cbase + s1]);
  int i0 = ((s0 >> 3) << 7) + cand_i[cbase + s0];
  int i1 = ((s1 >> 3) << 7) + cand_i[cbase + s1];
  if (v1 > v0) {
    const float tv = v0; v0 = v1; v1 = tv;
    const int ti = i0; i0 = i1; i1 = ti;
  }
  int keep = 0;
  for (int rnd = 0; rnd < 16; ++rnd) {
    float m = v0;
#pragma unroll
    for (int off = 32; off >= 1; off >>= 1) m = fmaxf(m, __shfl_xor(m, off));
    const unsigned long long bm = __ballot(v0 == m);
    const int owner = __ffsll(bm) - 1;
    const int oi = __shfl(i0, owner);
    if (lane == owner) { v0 = v1; i0 = i1; v1 = -3.0e38f; }
    if (lane == rnd) keep = oi;
  }

  // --- parallel exact rescore: group g (lane>>2) owns candidate g ---
  const int g = lane >> 2, p = lane & 3;
  const int jg = __shfl(keep, g);
  const float* Trow = T + (size_t)r * DDIM + (p << 8);
  const float* Hrow = H + ((size_t)(b << 11) + jg) * DDIM + (p << 8);
  double s = 0.0;
#pragma unroll 4
  for (int q = 0; q < 64; ++q) {
    const float4 tv = *reinterpret_cast<const float4*>(Trow + (q << 2));
    const float4 hv = *reinterpret_cast<const float4*>(Hrow + (q << 2));
    s = fma((double)tv.x, (double)hv.x, s);
    s = fma((double)tv.y, (double)hv.y, s);
    s = fma((double)tv.z, (double)hv.z, s);
    s = fma((double)tv.w, (double)hv.w, s);
  }
  s += __shfl_xor(s, 1);
  s += __shfl_xor(s, 2);
  const float aff = expf((float)s);

  // --- stable top-8 over the 16 (aff, j) pairs; redundant on all lanes ---
  float t8v[KSEL];
  int t8i[KSEL];
#pragma unroll
  for (int q = 0; q < KSEL; ++q) { t8v[q] = -1.0f; t8i[q] = IMAXC; }
  for (int c = 0; c < 16; ++c) {
    const float ac = __shfl(aff, c << 2);
    const int jc = __shfl(keep, c);
    const bool g7 = (ac > t8v[KSEL - 1]) ||
                    (ac == t8v[KSEL - 1] && jc < t8i[KSEL - 1]);
    if (g7) {
      float pv = ac; int pi = jc;
#pragma unroll
      for (int q = 0; q < KSEL; ++q) {
        const bool gi = (ac > t8v[q]) || (ac == t8v[q] && jc < t8i[q]);
        if (gi) {
          const float tv = t8v[q]; const int ti = t8i[q];
          t8v[q] = pv; t8i[q] = pi; pv = tv; pi = ti;
        }
      }
    }
  }
  if (lane == 0) {
    float sum = 0.0f;
#pragma unroll
    for (int q = 0; q < KSEL; ++q) sum += t8v[q];
    sum += 1e-8f;
    int c8 = KSEL;
#pragma unroll
    for (int q = 0; q < KSEL; ++q)
      if (t8i[q] == iloc) --c8;
    cnt[r] = c8;
#pragma unroll
    for (int q = 0; q < KSEL; ++q) {
      topi[(size_t)r * KSEL + q] = t8i[q];
      topw[(size_t)r * KSEL + q] = t8v[q] / sum;
    }
  }
}

// ---------------------------------------------------------------------------
// k4: exclusive prefix scan of per-row counts  -- UNCHANGED
// ---------------------------------------------------------------------------
__global__ __launch_bounds__(1024)
void k4_scan(const int* __restrict__ cnt, int* __restrict__ off) {
  __shared__ int part[1024];
  const int t = threadIdx.x;
  int loc[8];
  int s = 0;
#pragma unroll
  for (int i = 0; i < 8; ++i) { loc[i] = s; s += cnt[t * 8 + i]; }
  part[t] = s;
  __syncthreads();
  for (int d = 1; d < 1024; d <<= 1) {
    const int add = (t >= d) ? part[t - d] : 0;
    __syncthreads();
    part[t] += add;
    __syncthreads();
  }
  const int base = (t == 0) ? 0 : part[t - 1];
#pragma unroll
  for (int i = 0; i < 8; ++i) off[t * 8 + i] = base + loc[i];
}

// ---------------------------------------------------------------------------
// k5: emit edges  -- UNCHANGED
// ---------------------------------------------------------------------------
__global__ __launch_bounds__(256)
void k5_emit(const int* __restrict__ topi, const float* __restrict__ topw,
             const int* __restrict__ off, float* __restrict__ out, int E) {
  const int r = blockIdx.x * 256 + threadIdx.x;
  if (r >= NROWS) return;
  const int o = off[r];
  const int sloc = r & (SEQ - 1);
  const int bbase = r & ~(SEQ - 1);
  int e = 0;
#pragma unroll
  for (int p = 0; p < KSEL; ++p) {
    const int id = topi[(size_t)r * KSEL + p];
    const float w = topw[(size_t)r * KSEL + p];
    if (id != sloc) {
      const int pos = o + e;
      if (pos < E) {
        out[pos] = (float)r;
        out[(size_t)E + pos] = (float)(bbase + id);
        out[2 * (size_t)E + pos] = w;
      }
      ++e;
    }
  }
}

// ---------------------------------------------------------------------------
extern "C" void kernel_launch(void* const* d_in, const int* in_sizes, int n_in,
                              void* d_out, int out_size, void* d_ws,
                              size_t ws_size, hipStream_t stream) {
  const float* H = (const float*)d_in[0];      // [4,2048,1024]
  const float* Wphi = (const float*)d_in[1];   // [1024,1024]
  const float* Wpsi = (const float*)d_in[2];   // [1024,1024]
  float* out = (float*)d_out;
  const int E = out_size / 3;
  char* base = (char*)d_ws;

  // fast path needs T(32M) + Hb(16M) + Tb/Wc(16M) + cand(3M) + small(~0.6M)
  const size_t NEED_FAST = 70844420;
  if (ws_size >= NEED_FAST) {
    float* T = (float*)base;                                      // 32 MB
    unsigned short* Hb = (unsigned short*)(base + 33554432);      // 16 MB
    char* tbwc = base + 50331648;                                 // 16 MB
    float* Wc = (float*)tbwc;             // first 4 MB; dead before Tb write
    unsigned short* Tb = (unsigned short*)tbwc;                   // overlay
    unsigned short* cand_v = (unsigned short*)(base + 67108864);  // 2 MB
    unsigned char* cand_i = (unsigned char*)(base + 69206016);    // 1 MB
    int* topi = (int*)(base + 70254592);
    float* topw = (float*)(base + 70516736);
    int* cnt = (int*)(base + 70778880);
    int* off = (int*)(base + 70811648);
    int* sel = (int*)(base + 70844416);

    kprobe<<<dim3(1), 64, 0, stream>>>(sel);
    k0_mfma<<<dim3(16, 16), 256, 0, stream>>>(Wphi, Wpsi, Wc, sel);
    k0_repair<<<dim3(16, 16), 256, 0, stream>>>(Wphi, Wpsi, Wc, sel);
    k1_mfma<<<dim3(8, 64), 256, 0, stream>>>(H, Wc, T, sel);
    k1_repair<<<dim3(8, 64), 256, 0, stream>>>(H, Wc, T, sel);
    // bf16 conversion (Wc dead; Tb overlays it)
    kcvt2<<<dim3(4096), 256, 0, stream>>>(T, H, Tb, Hb);
    k2_mfma_bf<<<dim3(16, 16, 4), 256, 0, stream>>>(Tb, Hb, cand_v, cand_i);
    kr_rescore<<<dim3(NROWS / 4), 256, 0, stream>>>(T, H, cand_v, cand_i,
                                                    topi, topw, cnt);
    k4_scan<<<dim3(1), 1024, 0, stream>>>(cnt, off);
    k5_emit<<<dim3(NROWS / 256), 256, 0, stream>>>(topi, topw, off, out, E);
  } else {
    // R7 layout / path (proven at ~37.8 MB)
    float* T = (float*)base;                         // 32 MB
    char* regionX = base + 33554432;                 // 4 MB shared region
    float* Wc = (float*)regionX;
    unsigned short* cand_v = (unsigned short*)regionX;           // 2 MB
    unsigned char* cand_i = (unsigned char*)(regionX + 2097152); // 1 MB
    char* pp = regionX + 4194304;
    int* topi = (int*)pp;  pp += 262144;
    float* topw = (float*)pp; pp += 262144;
    int* cnt = (int*)pp;   pp += 32768;
    int* off = (int*)pp;   pp += 32768;
    int* sel = (int*)pp;

    kprobe<<<dim3(1), 64, 0, stream>>>(sel);
    k0_mfma<<<dim3(16, 16), 256, 0, stream>>>(Wphi, Wpsi, Wc, sel);
    k0_repair<<<dim3(16, 16), 256, 0, stream>>>(Wphi, Wpsi, Wc, sel);
    k1_mfma<<<dim3(8, 64), 256, 0, stream>>>(H, Wc, T, sel);
    k1_repair<<<dim3(8, 64), 256, 0, stream>>>(H, Wc, T, sel);
    k2_mfma<<<dim3(16, 16, 4), 256, 0, stream>>>(T, H, cand_v, cand_i);
    kr_rescore<<<dim3(NROWS / 4), 256, 0, stream>>>(T, H, cand_v, cand_i,
                                                    topi, topw, cnt);
    k4_scan<<<dim3(1), 1024, 0, stream>>>(cnt, off);
    k5_emit<<<dim3(NROWS / 256), 256, 0, stream>>>(topi, topw, off, out, E);
  }
}

// Round 9
// 592.107 us; speedup vs baseline: 1.0891x; 1.0891x over previous
//
#include <hip/hip_runtime.h>
#include <cmath>

#define SEQ 2048
#define DDIM 1024
#define NROWS 8192   // B*S
#define KSEL 8
#define IMAXC 0x7fffffff

typedef __attribute__((ext_vector_type(8))) short bf16x8;
typedef __attribute__((ext_vector_type(4))) float f32x4;
typedef __attribute__((ext_vector_type(4))) double f64x4;

__device__ __forceinline__ unsigned short f2bf(float f) {
  unsigned u = __builtin_bit_cast(unsigned, f);
  u = (u + 0x7fffu + ((u >> 16) & 1u)) >> 16;
  return (unsigned short)u;
}
__device__ __forceinline__ float bf2f(unsigned short h) {
  unsigned u = ((unsigned)h) << 16;
  return __builtin_bit_cast(float, u);
}
__device__ __forceinline__ unsigned pkbf(float a, float b) {
  unsigned r;
  asm("v_cvt_pk_bf16_f32 %0, %1, %2" : "=v"(r) : "v"(a), "v"(b));
  return r;
}
// D-fragment (row,col) within a 16x16 tile for f64 mfma, by probed layout sel
__device__ __forceinline__ void dmap(int sel, int lg, int lr, int rg,
                                     int& ri, int& ci) {
  switch (sel) {
    case 0:  ri = (lg << 2) + rg; ci = lr; break;
    case 1:  ri = lg + (rg << 2); ci = lr; break;
    case 2:  ri = lr; ci = (lg << 2) + rg; break;
    default: ri = lr; ci = lg + (rg << 2); break;
  }
}

// ---------------------------------------------------------------------------
// kprobe: one wave determines the f64-MFMA D layout (exact integer check).
// sel=4 -> unknown -> vector repair kernels take over. -- UNCHANGED (R7)
// ---------------------------------------------------------------------------
__global__ void kprobe(int* __restrict__ sel) {
  const int lane = threadIdx.x;
  const int lr = lane & 15, lg = lane >> 4;
  const double a = (double)(4 * lr + lg + 1);       // A[r=lr][k=lg]
  const double b = (double)(9 * lr + 5 * lg + 2);   // B[c=lr][k=lg] (asym)
  f64x4 d = (f64x4){0.0, 0.0, 0.0, 0.0};
  d = __builtin_amdgcn_mfma_f64_16x16x4f64(a, b, d, 0, 0, 0);
  int my = 4;
  for (int s = 3; s >= 0; --s) {
    bool ok = true;
    for (int rg = 0; rg < 4; ++rg) {
      int ri, ci;
      dmap(s, lg, lr, rg, ri, ci);
      double e = 0.0;
      for (int k = 0; k < 4; ++k)
        e += (double)(4 * ri + k + 1) * (double)(9 * ci + 5 * k + 2);
      ok = ok && (d[rg] == e);
    }
    if (__all(ok)) my = s;
  }
  if (lane == 0) sel[0] = my;
}

// ---------------------------------------------------------------------------
// k0_mfma: Wc = Wphi^T * Wpsi (TN, f64 MFMA). -- UNCHANGED (R7)
// ---------------------------------------------------------------------------
__global__ __launch_bounds__(256, 2)
void k0_mfma(const float* __restrict__ A, const float* __restrict__ B,
             float* __restrict__ C, const int* __restrict__ selp) {
  const int sel = selp[0];
  if (sel >= 4) return;
  __shared__ float As[32][72];
  __shared__ float Bs[32][72];
  const int tid = threadIdx.x;
  const int lane = tid & 63, w = tid >> 6;
  const int wr = w >> 1, wc = w & 1;
  const int lr = lane & 15, lg = lane >> 4;
  const int brow = blockIdx.y << 6, bcol = blockIdx.x << 6;
  const int kr = tid >> 3, c4 = (tid & 7) << 2;

  f64x4 acc[2][2];
#pragma unroll
  for (int mi = 0; mi < 2; ++mi)
#pragma unroll
    for (int nj = 0; nj < 2; ++nj)
      acc[mi][nj] = (f64x4){0.0, 0.0, 0.0, 0.0};

  const float* Ap = &A[(size_t)kr * DDIM + brow + c4];
  const float* Bp = &B[(size_t)kr * DDIM + bcol + c4];
  float4 pa0 = *reinterpret_cast<const float4*>(Ap);
  float4 pa1 = *reinterpret_cast<const float4*>(Ap + 32);
  float4 pb0 = *reinterpret_cast<const float4*>(Bp);
  float4 pb1 = *reinterpret_cast<const float4*>(Bp + 32);

  for (int k0 = 0; k0 < DDIM; k0 += 32) {
    __syncthreads();
    *reinterpret_cast<float4*>(&As[kr][c4]) = pa0;
    *reinterpret_cast<float4*>(&As[kr][c4 + 32]) = pa1;
    *reinterpret_cast<float4*>(&Bs[kr][c4]) = pb0;
    *reinterpret_cast<float4*>(&Bs[kr][c4 + 32]) = pb1;
    __syncthreads();
    if (k0 + 32 < DDIM) {
      const size_t nk = (size_t)(k0 + 32) * DDIM;
      pa0 = *reinterpret_cast<const float4*>(Ap + nk);
      pa1 = *reinterpret_cast<const float4*>(Ap + nk + 32);
      pb0 = *reinterpret_cast<const float4*>(Bp + nk);
      pb1 = *reinterpret_cast<const float4*>(Bp + nk + 32);
    }
#pragma unroll
    for (int kp = 0; kp < 8; ++kp) {
      const int ka = (kp << 2) + lg;
      double a[2], b[2];
#pragma unroll
      for (int mi = 0; mi < 2; ++mi)
        a[mi] = (double)As[ka][(wr << 5) + (mi << 4) + lr];
#pragma unroll
      for (int nj = 0; nj < 2; ++nj)
        b[nj] = (double)Bs[ka][(wc << 5) + (nj << 4) + lr];
#pragma unroll
      for (int mi = 0; mi < 2; ++mi)
#pragma unroll
        for (int nj = 0; nj < 2; ++nj)
          acc[mi][nj] = __builtin_amdgcn_mfma_f64_16x16x4f64(
              a[mi], b[nj], acc[mi][nj], 0, 0, 0);
    }
  }
#pragma unroll
  for (int mi = 0; mi < 2; ++mi)
#pragma unroll
    for (int nj = 0; nj < 2; ++nj)
#pragma unroll
      for (int rg = 0; rg < 4; ++rg) {
        int ri, ci;
        dmap(sel, lg, lr, rg, ri, ci);
        C[(size_t)(brow + (wr << 5) + (mi << 4) + ri) * DDIM +
          bcol + (wc << 5) + (nj << 4) + ci] = (float)acc[mi][nj][rg];
      }
}

// ---------------------------------------------------------------------------
// k0_repair: proven vector-f64 TN kernel; runs only if sel unknown. -- UNCHANGED
// ---------------------------------------------------------------------------
__global__ __launch_bounds__(256)
void k0_repair(const float* __restrict__ A, const float* __restrict__ B,
               float* __restrict__ C, const int* __restrict__ selp) {
  if (selp[0] < 4) return;
  __shared__ __align__(16) float As[32][68];
  __shared__ __align__(16) float Bs[32][68];
  const int tid = threadIdx.x;
  const int tx = tid & 15, ty = tid >> 4;
  const int brow = blockIdx.y << 6;
  const int bcol = blockIdx.x << 6;
  double acc[4][4] = {};
  for (int k0 = 0; k0 < DDIM; k0 += 32) {
#pragma unroll
    for (int i = 0; i < 2; ++i) {
      const int f = tid + (i << 8);
      const int r = f >> 4;
      const int c4 = (f & 15) << 2;
      *reinterpret_cast<float4*>(&As[r][c4]) =
          *reinterpret_cast<const float4*>(&A[(size_t)(k0 + r) * DDIM + brow + c4]);
      *reinterpret_cast<float4*>(&Bs[r][c4]) =
          *reinterpret_cast<const float4*>(&B[(size_t)(k0 + r) * DDIM + bcol + c4]);
    }
    __syncthreads();
#pragma unroll
    for (int kk = 0; kk < 32; ++kk) {
      const float4 a = *reinterpret_cast<const float4*>(&As[kk][ty << 2]);
      const float4 b = *reinterpret_cast<const float4*>(&Bs[kk][tx << 2]);
      const double ad[4] = {a.x, a.y, a.z, a.w};
      const double bd[4] = {b.x, b.y, b.z, b.w};
#pragma unroll
      for (int i = 0; i < 4; ++i)
#pragma unroll
        for (int j = 0; j < 4; ++j)
          acc[i][j] = fma(ad[i], bd[j], acc[i][j]);
    }
    __syncthreads();
  }
#pragma unroll
  for (int i = 0; i < 4; ++i) {
    float4 v = make_float4((float)acc[i][0], (float)acc[i][1],
                           (float)acc[i][2], (float)acc[i][3]);
    *reinterpret_cast<float4*>(
        &C[(size_t)(brow + (ty << 2) + i) * DDIM + bcol + (tx << 2)]) = v;
  }
}

// ---------------------------------------------------------------------------
// k1_mfma: T = H * Wc (NN, f64 MFMA), dbuf, 1 barrier/K-step. -- UNCHANGED (R7)
// ---------------------------------------------------------------------------
#define K1_STAGE(bi)                                              \
  do {                                                            \
    As[bi][akh + 0][ar] = pa0.x; As[bi][akh + 1][ar] = pa0.y;     \
    As[bi][akh + 2][ar] = pa0.z; As[bi][akh + 3][ar] = pa0.w;     \
    As[bi][akh + 4][ar] = pa1.x; As[bi][akh + 5][ar] = pa1.y;     \
    As[bi][akh + 6][ar] = pa1.z; As[bi][akh + 7][ar] = pa1.w;     \
    *reinterpret_cast<float4*>(&Bs[bi][bk][bc4]) = pb0;           \
    *reinterpret_cast<float4*>(&Bs[bi][bk][bc4 + 64]) = pb1;      \
  } while (0)

__global__ __launch_bounds__(256, 2)
void k1_mfma(const float* __restrict__ A, const float* __restrict__ B,
             float* __restrict__ C, const int* __restrict__ selp) {
  const int sel = selp[0];
  if (sel >= 4) return;
  __shared__ float As[2][16][144];
  __shared__ float Bs[2][16][144];
  const int tid = threadIdx.x;
  const int lin = blockIdx.y * 8 + blockIdx.x;          // 512 blocks
  const int nlin = (lin & 7) * 64 + (lin >> 3);         // bijective XCD swizzle
  const int brow = (nlin >> 3) << 7;
  const int bcol = (nlin & 7) << 7;
  const int lane = tid & 63, w = tid >> 6;
  const int wr = w >> 1, wc = w & 1;
  const int lr = lane & 15, lg = lane >> 4;
  const int ar = tid >> 1, akh = (tid & 1) << 3;
  const int bk = tid >> 4, bc4 = (tid & 15) << 2;

  f64x4 acc[4][4];
#pragma unroll
  for (int mi = 0; mi < 4; ++mi)
#pragma unroll
    for (int nj = 0; nj < 4; ++nj)
      acc[mi][nj] = (f64x4){0.0, 0.0, 0.0, 0.0};

  const float* Ap = &A[(size_t)(brow + ar) * DDIM + akh];
  const float* Bp = &B[(size_t)bk * DDIM + bcol + bc4];

  float4 pa0 = *reinterpret_cast<const float4*>(Ap);
  float4 pa1 = *reinterpret_cast<const float4*>(Ap + 4);
  float4 pb0 = *reinterpret_cast<const float4*>(Bp);
  float4 pb1 = *reinterpret_cast<const float4*>(Bp + 64);
  K1_STAGE(0);
  pa0 = *reinterpret_cast<const float4*>(Ap + 16);
  pa1 = *reinterpret_cast<const float4*>(Ap + 20);
  pb0 = *reinterpret_cast<const float4*>(Bp + (size_t)16 * DDIM);
  pb1 = *reinterpret_cast<const float4*>(Bp + (size_t)16 * DDIM + 64);

  for (int t = 0; t < 64; ++t) {
    __syncthreads();
    const int cur = t & 1;
    if (t < 63) {
      K1_STAGE(cur ^ 1);
      if (t < 62) {
        const size_t ko = (size_t)(t + 2) << 4;
        pa0 = *reinterpret_cast<const float4*>(Ap + ko);
        pa1 = *reinterpret_cast<const float4*>(Ap + ko + 4);
        pb0 = *reinterpret_cast<const float4*>(Bp + ko * DDIM);
        pb1 = *reinterpret_cast<const float4*>(Bp + ko * DDIM + 64);
      }
    }
#pragma unroll
    for (int kp = 0; kp < 4; ++kp) {
      const int ka = (kp << 2) + lg;
      double a[4], b[4];
#pragma unroll
      for (int mi = 0; mi < 4; ++mi)
        a[mi] = (double)As[cur][ka][(wr << 6) + (mi << 4) + lr];
#pragma unroll
      for (int nj = 0; nj < 4; ++nj)
        b[nj] = (double)Bs[cur][ka][(wc << 6) + (nj << 4) + lr];
#pragma unroll
      for (int mi = 0; mi < 4; ++mi)
#pragma unroll
        for (int nj = 0; nj < 4; ++nj)
          acc[mi][nj] = __builtin_amdgcn_mfma_f64_16x16x4f64(
              a[mi], b[nj], acc[mi][nj], 0, 0, 0);
    }
  }
#pragma unroll
  for (int mi = 0; mi < 4; ++mi)
#pragma unroll
    for (int nj = 0; nj < 4; ++nj)
#pragma unroll
      for (int rg = 0; rg < 4; ++rg) {
        int ri, ci;
        dmap(sel, lg, lr, rg, ri, ci);
        C[(size_t)(brow + (wr << 6) + (mi << 4) + ri) * DDIM +
          bcol + (wc << 6) + (nj << 4) + ci] = (float)acc[mi][nj][rg];
      }
}

// ---------------------------------------------------------------------------
// k1_repair: proven vector-f64 chain kernel; runs only if sel unknown. -- UNCHANGED
// ---------------------------------------------------------------------------
__global__ __launch_bounds__(256, 2)
void k1_repair(const float* __restrict__ A, const float* __restrict__ B,
               float* __restrict__ C, const int* __restrict__ selp) {
  if (selp[0] < 4) return;
  __shared__ double As[128][17];
  __shared__ double Bs[16][130];
  const int tid = threadIdx.x;
  const int lin = blockIdx.y * 8 + blockIdx.x;
  const int nlin = (lin & 7) * 64 + (lin >> 3);
  const int brow = (nlin >> 3) << 7;
  const int bcol = (nlin & 7) << 7;
  const int tx = tid & 15, ty = tid >> 4;
  const int ar = tid >> 1, aks = (tid & 1) << 3;
  const int bk = tid >> 4, btx = tid & 15;

  double acc[8][8];
#pragma unroll
  for (int i = 0; i < 8; ++i)
#pragma unroll
    for (int j = 0; j < 8; ++j) acc[i][j] = 0.0;

  const float* Aptr = &A[(size_t)(brow + ar) * DDIM + aks];
  const float* Bptr = &B[(size_t)bk * DDIM + bcol + (btx << 1)];

  float4 pa0, pa1;
  float2 pb[4];
  pa0 = *reinterpret_cast<const float4*>(Aptr);
  pa1 = *reinterpret_cast<const float4*>(Aptr + 4);
#pragma unroll
  for (int w = 0; w < 4; ++w)
    pb[w] = *reinterpret_cast<const float2*>(Bptr + (w << 5));

  for (int k0 = 0; k0 < DDIM; k0 += 16) {
    __syncthreads();
    As[ar][aks + 0] = (double)pa0.x; As[ar][aks + 1] = (double)pa0.y;
    As[ar][aks + 2] = (double)pa0.z; As[ar][aks + 3] = (double)pa0.w;
    As[ar][aks + 4] = (double)pa1.x; As[ar][aks + 5] = (double)pa1.y;
    As[ar][aks + 6] = (double)pa1.z; As[ar][aks + 7] = (double)pa1.w;
#pragma unroll
    for (int w = 0; w < 4; ++w) {
      Bs[bk][(btx << 1) + (w << 5) + 0] = (double)pb[w].x;
      Bs[bk][(btx << 1) + (w << 5) + 1] = (double)pb[w].y;
    }
    __syncthreads();
    if (k0 + 16 < DDIM) {
      pa0 = *reinterpret_cast<const float4*>(Aptr + k0 + 16);
      pa1 = *reinterpret_cast<const float4*>(Aptr + k0 + 20);
#pragma unroll
      for (int w = 0; w < 4; ++w)
        pb[w] = *reinterpret_cast<const float2*>(
            Bptr + (size_t)(k0 + 16) * DDIM + (w << 5));
    }
#pragma unroll 8
    for (int kk = 0; kk < 16; ++kk) {
      double a[8];
      double2 b[4];
#pragma unroll
      for (int i = 0; i < 8; ++i) a[i] = As[(ty << 3) + i][kk];
#pragma unroll
      for (int jj = 0; jj < 4; ++jj)
        b[jj] = *reinterpret_cast<const double2*>(&Bs[kk][(tx << 1) + (jj << 5)]);
#pragma unroll
      for (int i = 0; i < 8; ++i) {
#pragma unroll
        for (int jj = 0; jj < 4; ++jj) {
          acc[i][(jj << 1) + 0] = fma(a[i], b[jj].x, acc[i][(jj << 1) + 0]);
          acc[i][(jj << 1) + 1] = fma(a[i], b[jj].y, acc[i][(jj << 1) + 1]);
        }
      }
    }
  }
#pragma unroll
  for (int i = 0; i < 8; ++i) {
    float* crow = &C[(size_t)(brow + (ty << 3) + i) * DDIM + bcol + (tx << 1)];
#pragma unroll
    for (int jj = 0; jj < 4; ++jj) {
      float2 v = make_float2((float)acc[i][(jj << 1)],
                             (float)acc[i][(jj << 1) + 1]);
      *reinterpret_cast<float2*>(crow + (jj << 5)) = v;
    }
  }
}

// ---------------------------------------------------------------------------
// k2_mfma: approx scores = bf16(T) * bf16(H)^T, 256x256 tile, 512 threads,
// 8 waves (2x4), each wave 128x64 (acc 8x4). BK=64, slot-XOR swizzle, pkbf
// cvt in staging. Staging traffic halved vs 128^2 (512 MB total).
// Epilogue: 4 phases x 64 rows; 8 threads/row scan 32 cols; ordered merge
// -> per-row top-8 of the block's 256 cols -> cand (64 slots/row).
// ---------------------------------------------------------------------------
__global__ __launch_bounds__(512, 1)
void k2_mfma(const float* __restrict__ T, const float* __restrict__ H,
             unsigned short* __restrict__ cand_v,
             unsigned char* __restrict__ cand_i) {
  __shared__ union {
    unsigned short stage[2][256 * 64];   // 64 KB
    float Sl[64][264];                   // 67.6 KB
    struct {
      float mv[512][8];                  // 16 KB
      unsigned char mi[512][8];          // 4 KB
    } mg;
  } u;
  const int tid = threadIdx.x;
  const int lane = tid & 63;
  const int w = tid >> 6;               // 0..7
  const int wr = w >> 2, wc = w & 3;    // 2 x 4 wave grid
  const int lr = lane & 15, lg = lane >> 4;
  const int z = blockIdx.z;
  const int bx = blockIdx.x;            // col block 0..7
  const int brow = blockIdx.y << 8, bcol = bx << 8;
  const int row0g = z * SEQ + brow;
  const int col0g = z * SEQ + bcol;

  f32x4 acc[8][4];
#pragma unroll
  for (int mi = 0; mi < 8; ++mi)
#pragma unroll
    for (int nj = 0; nj < 4; ++nj)
      acc[mi][nj] = (f32x4){0.f, 0.f, 0.f, 0.f};

  for (int k0 = 0; k0 < DDIM; k0 += 64) {
    __syncthreads();
#pragma unroll
    for (int q = 0; q < 4; ++q) {
      const int c = (q << 9) + tid;          // 0..2047 linear 16B chunk
      const int row = c >> 3, slot = c & 7;
      const int gs = slot ^ (row & 7);       // inverse-swizzled source slot
      {
        const float* s = &T[(size_t)(row0g + row) * DDIM + k0 + (gs << 3)];
        const float4 f0 = *reinterpret_cast<const float4*>(s);
        const float4 f1 = *reinterpret_cast<const float4*>(s + 4);
        uint4 o;
        o.x = pkbf(f0.x, f0.y); o.y = pkbf(f0.z, f0.w);
        o.z = pkbf(f1.x, f1.y); o.w = pkbf(f1.z, f1.w);
        *reinterpret_cast<uint4*>(&u.stage[0][c << 3]) = o;
      }
      {
        const float* s = &H[(size_t)(col0g + row) * DDIM + k0 + (gs << 3)];
        const float4 f0 = *reinterpret_cast<const float4*>(s);
        const float4 f1 = *reinterpret_cast<const float4*>(s + 4);
        uint4 o;
        o.x = pkbf(f0.x, f0.y); o.y = pkbf(f0.z, f0.w);
        o.z = pkbf(f1.x, f1.y); o.w = pkbf(f1.z, f1.w);
        *reinterpret_cast<uint4*>(&u.stage[1][c << 3]) = o;
      }
    }
    __syncthreads();
#pragma unroll
    for (int kh = 0; kh < 2; ++kh) {
      const int sl = (kh << 2) + lg;
      bf16x8 bfv[4];
#pragma unroll
      for (int nj = 0; nj < 4; ++nj) {
        const int rb = (wc << 6) + (nj << 4) + lr;
        bfv[nj] = *reinterpret_cast<const bf16x8*>(
            &u.stage[1][(rb << 6) + ((sl ^ (rb & 7)) << 3)]);
      }
#pragma unroll
      for (int mi = 0; mi < 8; ++mi) {
        const int ra = (wr << 7) + (mi << 4) + lr;
        const bf16x8 af = *reinterpret_cast<const bf16x8*>(
            &u.stage[0][(ra << 6) + ((sl ^ (ra & 7)) << 3)]);
#pragma unroll
        for (int nj = 0; nj < 4; ++nj)
          acc[mi][nj] = __builtin_amdgcn_mfma_f32_16x16x32_bf16(
              af, bfv[nj], acc[mi][nj], 0, 0, 0);
      }
    }
  }

  // epilogue: 4 phases of 64 rows
  const int srow = tid >> 3;     // 0..63
  const int qd = tid & 7;        // eighth (32 cols each)
#pragma unroll
  for (int p = 0; p < 4; ++p) {
    __syncthreads();
    if (wr == (p >> 1)) {
      const int mib = (p & 1) << 2;
#pragma unroll
      for (int mi2 = 0; mi2 < 4; ++mi2)
#pragma unroll
        for (int nj = 0; nj < 4; ++nj)
#pragma unroll
          for (int rg = 0; rg < 4; ++rg)
            u.Sl[(mi2 << 4) + (lg << 2) + rg][(wc << 6) + (nj << 4) + lr] =
                acc[mib + mi2][nj][rg];
    }
    __syncthreads();
    // scan 32 cols into register top-8 (stream idx increasing -> stable)
    float v[KSEL];
    int ci[KSEL];
#pragma unroll
    for (int s = 0; s < KSEL; ++s) { v[s] = -3.0e38f; ci[s] = 0; }
    const int c0 = qd << 5;
    for (int c = 0; c < 32; ++c) {
      const float x = u.Sl[srow][c0 + c];
      if (x > v[KSEL - 1]) {
        float pv = x; int pc = c0 + c;
#pragma unroll
        for (int s = 0; s < KSEL; ++s) {
          if (x > v[s]) {
            const float tv = v[s]; const int tc = ci[s];
            v[s] = pv; ci[s] = pc; pv = tv; pc = tc;
          }
        }
      }
    }
    __syncthreads();   // all Sl reads done before mg overlay
#pragma unroll
    for (int s = 0; s < KSEL; ++s) {
      u.mg.mv[tid][s] = v[s];
      u.mg.mi[tid][s] = (unsigned char)ci[s];
    }
    __syncthreads();
    if (qd == 0) {
      // merge 8 eighth-lists in col-ascending order; strict > insertion
      // reproduces the (value desc, col asc) order of a full 0..255 scan.
      float fv[KSEL];
      int fi[KSEL];
#pragma unroll
      for (int s = 0; s < KSEL; ++s) { fv[s] = -3.0e38f; fi[s] = 0; }
#pragma unroll
      for (int t = 0; t < 8; ++t) {
#pragma unroll
        for (int s = 0; s < KSEL; ++s) {
          const float x = u.mg.mv[tid + t][s];
          const int idx = u.mg.mi[tid + t][s];
          if (x > fv[KSEL - 1]) {
            float pv = x; int pc = idx;
#pragma unroll
            for (int s2 = 0; s2 < KSEL; ++s2) {
              if (x > fv[s2]) {
                const float tv = fv[s2]; const int tc = fi[s2];
                fv[s2] = pv; fi[s2] = pc; pv = tv; pc = tc;
              }
            }
          }
        }
      }
      const size_t base =
          (size_t)(row0g + (p << 6) + srow) * 64 + ((size_t)bx << 3);
#pragma unroll
      for (int s = 0; s < KSEL; ++s) {
        cand_v[base + s] = f2bf(fv[s]);
        cand_i[base + s] = (unsigned char)fi[s];
      }
    }
  }
}

// ---------------------------------------------------------------------------
// kr_rescore: extraction of approx-top-16 from 64 cands (1/lane, 16 rounds
// of wave-max) + SERIAL exact f64 rescore (proven R7 pattern: full-wave
// coalesced 1KB reads per candidate) + stable top-8 + weights + counts.
// ---------------------------------------------------------------------------
__global__ __launch_bounds__(256)
void kr_rescore(const float* __restrict__ T, const float* __restrict__ H,
                const unsigned short* __restrict__ cand_v,
                const unsigned char* __restrict__ cand_i,
                int* __restrict__ topi, float* __restrict__ topw,
                int* __restrict__ cnt) {
  const int tid = threadIdx.x, lane = tid & 63, w = tid >> 6;
  const int r = blockIdx.x * 4 + w;
  const int b = r >> 11, iloc = r & (SEQ - 1);

  // --- extraction: 64 candidates, one per lane ---
  const size_t cbase = (size_t)r * 64;
  float v0 = bf2f(cand_v[cbase + lane]);
  int i0 = ((lane >> 3) << 8) + cand_i[cbase + lane];
  int keep = 0;
  for (int rnd = 0; rnd < 16; ++rnd) {
    float m = v0;
#pragma unroll
    for (int off = 32; off >= 1; off >>= 1) m = fmaxf(m, __shfl_xor(m, off));
    const unsigned long long bm = __ballot(v0 == m);
    const int owner = __ffsll(bm) - 1;
    const int oi = __shfl(i0, owner);
    if (lane == owner) v0 = -3.0e38f;
    if (lane == rnd) keep = oi;
  }

  // --- serial exact rescore (R7-proven access pattern) ---
  const float* Trow = T + (size_t)r * DDIM;
  float4 t4[4];
#pragma unroll
  for (int q = 0; q < 4; ++q)
    t4[q] = *reinterpret_cast<const float4*>(&Trow[(q << 8) + (lane << 2)]);

  float t8v[KSEL];
  int t8i[KSEL];
#pragma unroll
  for (int p = 0; p < KSEL; ++p) { t8v[p] = -1.0f; t8i[p] = IMAXC; }

  for (int c = 0; c < 16; ++c) {
    const int j = __shfl(keep, c);
    const float* Hrow = H + ((size_t)(b << 11) + j) * DDIM;
    double s = 0.0;
#pragma unroll
    for (int q = 0; q < 4; ++q) {
      const float4 h = *reinterpret_cast<const float4*>(&Hrow[(q << 8) + (lane << 2)]);
      s = fma((double)t4[q].x, (double)h.x, s);
      s = fma((double)t4[q].y, (double)h.y, s);
      s = fma((double)t4[q].z, (double)h.z, s);
      s = fma((double)t4[q].w, (double)h.w, s);
    }
#pragma unroll
    for (int off = 1; off < 64; off <<= 1) s += __shfl_xor(s, off);
    const float aff = expf((float)s);
    const bool g7 = (aff > t8v[KSEL - 1]) ||
                    (aff == t8v[KSEL - 1] && j < t8i[KSEL - 1]);
    if (g7) {
      float pv = aff; int pi = j;
#pragma unroll
      for (int p = 0; p < KSEL; ++p) {
        const bool g = (aff > t8v[p]) || (aff == t8v[p] && j < t8i[p]);
        if (g) {
          const float tv = t8v[p]; const int ti = t8i[p];
          t8v[p] = pv; t8i[p] = pi; pv = tv; pi = ti;
        }
      }
    }
  }
  if (lane == 0) {
    float sum = 0.0f;
#pragma unroll
    for (int p = 0; p < KSEL; ++p) sum += t8v[p];
    sum += 1e-8f;
    int c8 = KSEL;
#pragma unroll
    for (int p = 0; p < KSEL; ++p)
      if (t8i[p] == iloc) --c8;
    cnt[r] = c8;
#pragma unroll
    for (int p = 0; p < KSEL; ++p) {
      topi[(size_t)r * KSEL + p] = t8i[p];
      topw[(size_t)r * KSEL + p] = t8v[p] / sum;
    }
  }
}

// ---------------------------------------------------------------------------
// k4: exclusive prefix scan of per-row counts  -- UNCHANGED
// ---------------------------------------------------------------------------
__global__ __launch_bounds__(1024)
void k4_scan(const int* __restrict__ cnt, int* __restrict__ off) {
  __shared__ int part[1024];
  const int t = threadIdx.x;
  int loc[8];
  int s = 0;
#pragma unroll
  for (int i = 0; i < 8; ++i) { loc[i] = s; s += cnt[t * 8 + i]; }
  part[t] = s;
  __syncthreads();
  for (int d = 1; d < 1024; d <<= 1) {
    const int add = (t >= d) ? part[t - d] : 0;
    __syncthreads();
    part[t] += add;
    __syncthreads();
  }
  const int base = (t == 0) ? 0 : part[t - 1];
#pragma unroll
  for (int i = 0; i < 8; ++i) off[t * 8 + i] = base + loc[i];
}

// ---------------------------------------------------------------------------
// k5: emit edges  -- UNCHANGED
// ---------------------------------------------------------------------------
__global__ __launch_bounds__(256)
void k5_emit(const int* __restrict__ topi, const float* __restrict__ topw,
             const int* __restrict__ off, float* __restrict__ out, int E) {
  const int r = blockIdx.x * 256 + threadIdx.x;
  if (r >= NROWS) return;
  const int o = off[r];
  const int sloc = r & (SEQ - 1);
  const int bbase = r & ~(SEQ - 1);
  int e = 0;
#pragma unroll
  for (int p = 0; p < KSEL; ++p) {
    const int id = topi[(size_t)r * KSEL + p];
    const float w = topw[(size_t)r * KSEL + p];
    if (id != sloc) {
      const int pos = o + e;
      if (pos < E) {
        out[pos] = (float)r;
        out[(size_t)E + pos] = (float)(bbase + id);
        out[2 * (size_t)E + pos] = w;
      }
      ++e;
    }
  }
}

// ---------------------------------------------------------------------------
extern "C" void kernel_launch(void* const* d_in, const int* in_sizes, int n_in,
                              void* d_out, int out_size, void* d_ws,
                              size_t ws_size, hipStream_t stream) {
  const float* H = (const float*)d_in[0];      // [4,2048,1024]
  const float* Wphi = (const float*)d_in[1];   // [1024,1024]
  const float* Wpsi = (const float*)d_in[2];   // [1024,1024]
  float* out = (float*)d_out;
  const int E = out_size / 3;

  char* base = (char*)d_ws;
  float* T = (float*)base;                         // 32 MB
  char* regionX = base + 33554432;                 // 4 MB shared region
  float* Wc = (float*)regionX;                     //   Wc (dead after k1)
  unsigned short* cand_v = (unsigned short*)regionX;           // 1 MB used
  unsigned char* cand_i = (unsigned char*)(regionX + 2097152); // 0.5 MB used
  char* pp = regionX + 4194304;
  int* topi = (int*)pp;  pp += 262144;
  float* topw = (float*)pp; pp += 262144;
  int* cnt = (int*)pp;   pp += 32768;
  int* off = (int*)pp;   pp += 32768;
  int* sel = (int*)pp;

  // probe f64-MFMA D layout (writes sel in-stream before any consumer)
  kprobe<<<dim3(1), 64, 0, stream>>>(sel);
  // Wc = Wphi^T * Wpsi  (f64 MFMA; vector repair if layout unknown)
  k0_mfma<<<dim3(16, 16), 256, 0, stream>>>(Wphi, Wpsi, Wc, sel);
  k0_repair<<<dim3(16, 16), 256, 0, stream>>>(Wphi, Wpsi, Wc, sel);
  // T = H * Wc  (f64 MFMA, dbuf; vector repair if layout unknown)
  k1_mfma<<<dim3(8, 64), 256, 0, stream>>>(H, Wc, T, sel);
  k1_repair<<<dim3(8, 64), 256, 0, stream>>>(H, Wc, T, sel);
  // approx MFMA scores, 256^2 tile + fused block-top-8 (Wc dead; cand reuses)
  k2_mfma<<<dim3(8, 8, 4), 512, 0, stream>>>(T, H, cand_v, cand_i);
  // fused extraction + exact f64 rescore + stable top-8 + weights + counts
  kr_rescore<<<dim3(NROWS / 4), 256, 0, stream>>>(T, H, cand_v, cand_i,
                                                  topi, topw, cnt);
  // prefix scan + emit
  k4_scan<<<dim3(1), 1024, 0, stream>>>(cnt, off);
  k5_emit<<<dim3(NROWS / 256), 256, 0, stream>>>(topi, topw, off, out, E);
}

// Round 10
// 563.014 us; speedup vs baseline: 1.1454x; 1.0517x over previous
//
#include <hip/hip_runtime.h>
#include <cmath>

#define SEQ 2048
#define DDIM 1024
#define NROWS 8192   // B*S
#define KSEL 8
#define IMAXC 0x7fffffff

typedef __attribute__((ext_vector_type(8))) short bf16x8;
typedef __attribute__((ext_vector_type(4))) float f32x4;
typedef __attribute__((ext_vector_type(4))) double f64x4;

__device__ __forceinline__ unsigned short f2bf(float f) {
  unsigned u = __builtin_bit_cast(unsigned, f);
  u = (u + 0x7fffu + ((u >> 16) & 1u)) >> 16;
  return (unsigned short)u;
}
__device__ __forceinline__ float bf2f(unsigned short h) {
  unsigned u = ((unsigned)h) << 16;
  return __builtin_bit_cast(float, u);
}
__device__ __forceinline__ unsigned pkbf(float a, float b) {
  unsigned r;
  asm("v_cvt_pk_bf16_f32 %0, %1, %2" : "=v"(r) : "v"(a), "v"(b));
  return r;
}
// D-fragment (row,col) within a 16x16 tile for f64 mfma, by probed layout sel
__device__ __forceinline__ void dmap(int sel, int lg, int lr, int rg,
                                     int& ri, int& ci) {
  switch (sel) {
    case 0:  ri = (lg << 2) + rg; ci = lr; break;
    case 1:  ri = lg + (rg << 2); ci = lr; break;
    case 2:  ri = lr; ci = (lg << 2) + rg; break;
    default: ri = lr; ci = lg + (rg << 2); break;
  }
}

// ---------------------------------------------------------------------------
// kprobe: one wave determines the f64-MFMA D layout (exact integer check).
// sel=4 -> unknown -> vector repair kernels take over. -- UNCHANGED
// ---------------------------------------------------------------------------
__global__ void kprobe(int* __restrict__ sel) {
  const int lane = threadIdx.x;
  const int lr = lane & 15, lg = lane >> 4;
  const double a = (double)(4 * lr + lg + 1);       // A[r=lr][k=lg]
  const double b = (double)(9 * lr + 5 * lg + 2);   // B[c=lr][k=lg] (asym)
  f64x4 d = (f64x4){0.0, 0.0, 0.0, 0.0};
  d = __builtin_amdgcn_mfma_f64_16x16x4f64(a, b, d, 0, 0, 0);
  int my = 4;
  for (int s = 3; s >= 0; --s) {
    bool ok = true;
    for (int rg = 0; rg < 4; ++rg) {
      int ri, ci;
      dmap(s, lg, lr, rg, ri, ci);
      double e = 0.0;
      for (int k = 0; k < 4; ++k)
        e += (double)(4 * ri + k + 1) * (double)(9 * ci + 5 * k + 2);
      ok = ok && (d[rg] == e);
    }
    if (__all(ok)) my = s;
  }
  if (lane == 0) sel[0] = my;
}

// ---------------------------------------------------------------------------
// k0_mfma: Wc = Wphi^T * Wpsi (TN, f64 MFMA), NOW double-buffered with ONE
// barrier per K-step. Identical mfma chain/order => Wc bitwise-unchanged.
// ---------------------------------------------------------------------------
#define K0_STAGE(bi)                                        \
  do {                                                      \
    *reinterpret_cast<float4*>(&As[bi][kr][c4]) = pa0;      \
    *reinterpret_cast<float4*>(&As[bi][kr][c4 + 32]) = pa1; \
    *reinterpret_cast<float4*>(&Bs[bi][kr][c4]) = pb0;      \
    *reinterpret_cast<float4*>(&Bs[bi][kr][c4 + 32]) = pb1; \
  } while (0)

__global__ __launch_bounds__(256, 2)
void k0_mfma(const float* __restrict__ A, const float* __restrict__ B,
             float* __restrict__ C, const int* __restrict__ selp) {
  const int sel = selp[0];
  if (sel >= 4) return;
  __shared__ float As[2][32][72];
  __shared__ float Bs[2][32][72];
  const int tid = threadIdx.x;
  const int lane = tid & 63, w = tid >> 6;
  const int wr = w >> 1, wc = w & 1;
  const int lr = lane & 15, lg = lane >> 4;
  const int brow = blockIdx.y << 6, bcol = blockIdx.x << 6;
  const int kr = tid >> 3, c4 = (tid & 7) << 2;

  f64x4 acc[2][2];
#pragma unroll
  for (int mi = 0; mi < 2; ++mi)
#pragma unroll
    for (int nj = 0; nj < 2; ++nj)
      acc[mi][nj] = (f64x4){0.0, 0.0, 0.0, 0.0};

  const float* Ap = &A[(size_t)kr * DDIM + brow + c4];
  const float* Bp = &B[(size_t)kr * DDIM + bcol + c4];
  float4 pa0 = *reinterpret_cast<const float4*>(Ap);
  float4 pa1 = *reinterpret_cast<const float4*>(Ap + 32);
  float4 pb0 = *reinterpret_cast<const float4*>(Bp);
  float4 pb1 = *reinterpret_cast<const float4*>(Bp + 32);
  K0_STAGE(0);
  {
    const size_t nk = (size_t)32 * DDIM;
    pa0 = *reinterpret_cast<const float4*>(Ap + nk);
    pa1 = *reinterpret_cast<const float4*>(Ap + nk + 32);
    pb0 = *reinterpret_cast<const float4*>(Bp + nk);
    pb1 = *reinterpret_cast<const float4*>(Bp + nk + 32);
  }

  for (int t = 0; t < 32; ++t) {
    __syncthreads();
    const int cur = t & 1;
    if (t < 31) {
      K0_STAGE(cur ^ 1);
      if (t < 30) {
        const size_t nk = (size_t)(t + 2) * 32 * DDIM;
        pa0 = *reinterpret_cast<const float4*>(Ap + nk);
        pa1 = *reinterpret_cast<const float4*>(Ap + nk + 32);
        pb0 = *reinterpret_cast<const float4*>(Bp + nk);
        pb1 = *reinterpret_cast<const float4*>(Bp + nk + 32);
      }
    }
    __builtin_amdgcn_s_setprio(1);
#pragma unroll
    for (int kp = 0; kp < 8; ++kp) {
      const int ka = (kp << 2) + lg;
      double a[2], b[2];
#pragma unroll
      for (int mi = 0; mi < 2; ++mi)
        a[mi] = (double)As[cur][ka][(wr << 5) + (mi << 4) + lr];
#pragma unroll
      for (int nj = 0; nj < 2; ++nj)
        b[nj] = (double)Bs[cur][ka][(wc << 5) + (nj << 4) + lr];
#pragma unroll
      for (int mi = 0; mi < 2; ++mi)
#pragma unroll
        for (int nj = 0; nj < 2; ++nj)
          acc[mi][nj] = __builtin_amdgcn_mfma_f64_16x16x4f64(
              a[mi], b[nj], acc[mi][nj], 0, 0, 0);
    }
    __builtin_amdgcn_s_setprio(0);
  }
#pragma unroll
  for (int mi = 0; mi < 2; ++mi)
#pragma unroll
    for (int nj = 0; nj < 2; ++nj)
#pragma unroll
      for (int rg = 0; rg < 4; ++rg) {
        int ri, ci;
        dmap(sel, lg, lr, rg, ri, ci);
        C[(size_t)(brow + (wr << 5) + (mi << 4) + ri) * DDIM +
          bcol + (wc << 5) + (nj << 4) + ci] = (float)acc[mi][nj][rg];
      }
}

// ---------------------------------------------------------------------------
// k0_repair: proven vector-f64 TN kernel; runs only if sel unknown. -- UNCHANGED
// ---------------------------------------------------------------------------
__global__ __launch_bounds__(256)
void k0_repair(const float* __restrict__ A, const float* __restrict__ B,
               float* __restrict__ C, const int* __restrict__ selp) {
  if (selp[0] < 4) return;
  __shared__ __align__(16) float As[32][68];
  __shared__ __align__(16) float Bs[32][68];
  const int tid = threadIdx.x;
  const int tx = tid & 15, ty = tid >> 4;
  const int brow = blockIdx.y << 6;
  const int bcol = blockIdx.x << 6;
  double acc[4][4] = {};
  for (int k0 = 0; k0 < DDIM; k0 += 32) {
#pragma unroll
    for (int i = 0; i < 2; ++i) {
      const int f = tid + (i << 8);
      const int r = f >> 4;
      const int c4 = (f & 15) << 2;
      *reinterpret_cast<float4*>(&As[r][c4]) =
          *reinterpret_cast<const float4*>(&A[(size_t)(k0 + r) * DDIM + brow + c4]);
      *reinterpret_cast<float4*>(&Bs[r][c4]) =
          *reinterpret_cast<const float4*>(&B[(size_t)(k0 + r) * DDIM + bcol + c4]);
    }
    __syncthreads();
#pragma unroll
    for (int kk = 0; kk < 32; ++kk) {
      const float4 a = *reinterpret_cast<const float4*>(&As[kk][ty << 2]);
      const float4 b = *reinterpret_cast<const float4*>(&Bs[kk][tx << 2]);
      const double ad[4] = {a.x, a.y, a.z, a.w};
      const double bd[4] = {b.x, b.y, b.z, b.w};
#pragma unroll
      for (int i = 0; i < 4; ++i)
#pragma unroll
        for (int j = 0; j < 4; ++j)
          acc[i][j] = fma(ad[i], bd[j], acc[i][j]);
    }
    __syncthreads();
  }
#pragma unroll
  for (int i = 0; i < 4; ++i) {
    float4 v = make_float4((float)acc[i][0], (float)acc[i][1],
                           (float)acc[i][2], (float)acc[i][3]);
    *reinterpret_cast<float4*>(
        &C[(size_t)(brow + (ty << 2) + i) * DDIM + bcol + (tx << 2)]) = v;
  }
}

// ---------------------------------------------------------------------------
// k1_mfma: T = H * Wc (NN, f64 MFMA), dbuf, 1 barrier/K-step, + setprio
// around the MFMA cluster (scheduler hint only; numerics identical).
// ---------------------------------------------------------------------------
#define K1_STAGE(bi)                                              \
  do {                                                            \
    As[bi][akh + 0][ar] = pa0.x; As[bi][akh + 1][ar] = pa0.y;     \
    As[bi][akh + 2][ar] = pa0.z; As[bi][akh + 3][ar] = pa0.w;     \
    As[bi][akh + 4][ar] = pa1.x; As[bi][akh + 5][ar] = pa1.y;     \
    As[bi][akh + 6][ar] = pa1.z; As[bi][akh + 7][ar] = pa1.w;     \
    *reinterpret_cast<float4*>(&Bs[bi][bk][bc4]) = pb0;           \
    *reinterpret_cast<float4*>(&Bs[bi][bk][bc4 + 64]) = pb1;      \
  } while (0)

__global__ __launch_bounds__(256, 2)
void k1_mfma(const float* __restrict__ A, const float* __restrict__ B,
             float* __restrict__ C, const int* __restrict__ selp) {
  const int sel = selp[0];
  if (sel >= 4) return;
  __shared__ float As[2][16][144];
  __shared__ float Bs[2][16][144];
  const int tid = threadIdx.x;
  const int lin = blockIdx.y * 8 + blockIdx.x;          // 512 blocks
  const int nlin = (lin & 7) * 64 + (lin >> 3);         // bijective XCD swizzle
  const int brow = (nlin >> 3) << 7;
  const int bcol = (nlin & 7) << 7;
  const int lane = tid & 63, w = tid >> 6;
  const int wr = w >> 1, wc = w & 1;
  const int lr = lane & 15, lg = lane >> 4;
  const int ar = tid >> 1, akh = (tid & 1) << 3;
  const int bk = tid >> 4, bc4 = (tid & 15) << 2;

  f64x4 acc[4][4];
#pragma unroll
  for (int mi = 0; mi < 4; ++mi)
#pragma unroll
    for (int nj = 0; nj < 4; ++nj)
      acc[mi][nj] = (f64x4){0.0, 0.0, 0.0, 0.0};

  const float* Ap = &A[(size_t)(brow + ar) * DDIM + akh];
  const float* Bp = &B[(size_t)bk * DDIM + bcol + bc4];

  float4 pa0 = *reinterpret_cast<const float4*>(Ap);
  float4 pa1 = *reinterpret_cast<const float4*>(Ap + 4);
  float4 pb0 = *reinterpret_cast<const float4*>(Bp);
  float4 pb1 = *reinterpret_cast<const float4*>(Bp + 64);
  K1_STAGE(0);
  pa0 = *reinterpret_cast<const float4*>(Ap + 16);
  pa1 = *reinterpret_cast<const float4*>(Ap + 20);
  pb0 = *reinterpret_cast<const float4*>(Bp + (size_t)16 * DDIM);
  pb1 = *reinterpret_cast<const float4*>(Bp + (size_t)16 * DDIM + 64);

  for (int t = 0; t < 64; ++t) {
    __syncthreads();
    const int cur = t & 1;
    if (t < 63) {
      K1_STAGE(cur ^ 1);
      if (t < 62) {
        const size_t ko = (size_t)(t + 2) << 4;
        pa0 = *reinterpret_cast<const float4*>(Ap + ko);
        pa1 = *reinterpret_cast<const float4*>(Ap + ko + 4);
        pb0 = *reinterpret_cast<const float4*>(Bp + ko * DDIM);
        pb1 = *reinterpret_cast<const float4*>(Bp + ko * DDIM + 64);
      }
    }
    __builtin_amdgcn_s_setprio(1);
#pragma unroll
    for (int kp = 0; kp < 4; ++kp) {
      const int ka = (kp << 2) + lg;
      double a[4], b[4];
#pragma unroll
      for (int mi = 0; mi < 4; ++mi)
        a[mi] = (double)As[cur][ka][(wr << 6) + (mi << 4) + lr];
#pragma unroll
      for (int nj = 0; nj < 4; ++nj)
        b[nj] = (double)Bs[cur][ka][(wc << 6) + (nj << 4) + lr];
#pragma unroll
      for (int mi = 0; mi < 4; ++mi)
#pragma unroll
        for (int nj = 0; nj < 4; ++nj)
          acc[mi][nj] = __builtin_amdgcn_mfma_f64_16x16x4f64(
              a[mi], b[nj], acc[mi][nj], 0, 0, 0);
    }
    __builtin_amdgcn_s_setprio(0);
  }
#pragma unroll
  for (int mi = 0; mi < 4; ++mi)
#pragma unroll
    for (int nj = 0; nj < 4; ++nj)
#pragma unroll
      for (int rg = 0; rg < 4; ++rg) {
        int ri, ci;
        dmap(sel, lg, lr, rg, ri, ci);
        C[(size_t)(brow + (wr << 6) + (mi << 4) + ri) * DDIM +
          bcol + (wc << 6) + (nj << 4) + ci] = (float)acc[mi][nj][rg];
      }
}

// ---------------------------------------------------------------------------
// k1_repair: proven vector-f64 chain kernel; runs only if sel unknown. -- UNCHANGED
// ---------------------------------------------------------------------------
__global__ __launch_bounds__(256, 2)
void k1_repair(const float* __restrict__ A, const float* __restrict__ B,
               float* __restrict__ C, const int* __restrict__ selp) {
  if (selp[0] < 4) return;
  __shared__ double As[128][17];
  __shared__ double Bs[16][130];
  const int tid = threadIdx.x;
  const int lin = blockIdx.y * 8 + blockIdx.x;
  const int nlin = (lin & 7) * 64 + (lin >> 3);
  const int brow = (nlin >> 3) << 7;
  const int bcol = (nlin & 7) << 7;
  const int tx = tid & 15, ty = tid >> 4;
  const int ar = tid >> 1, aks = (tid & 1) << 3;
  const int bk = tid >> 4, btx = tid & 15;

  double acc[8][8];
#pragma unroll
  for (int i = 0; i < 8; ++i)
#pragma unroll
    for (int j = 0; j < 8; ++j) acc[i][j] = 0.0;

  const float* Aptr = &A[(size_t)(brow + ar) * DDIM + aks];
  const float* Bptr = &B[(size_t)bk * DDIM + bcol + (btx << 1)];

  float4 pa0, pa1;
  float2 pb[4];
  pa0 = *reinterpret_cast<const float4*>(Aptr);
  pa1 = *reinterpret_cast<const float4*>(Aptr + 4);
#pragma unroll
  for (int w = 0; w < 4; ++w)
    pb[w] = *reinterpret_cast<const float2*>(Bptr + (w << 5));

  for (int k0 = 0; k0 < DDIM; k0 += 16) {
    __syncthreads();
    As[ar][aks + 0] = (double)pa0.x; As[ar][aks + 1] = (double)pa0.y;
    As[ar][aks + 2] = (double)pa0.z; As[ar][aks + 3] = (double)pa0.w;
    As[ar][aks + 4] = (double)pa1.x; As[ar][aks + 5] = (double)pa1.y;
    As[ar][aks + 6] = (double)pa1.z; As[ar][aks + 7] = (double)pa1.w;
#pragma unroll
    for (int w = 0; w < 4; ++w) {
      Bs[bk][(btx << 1) + (w << 5) + 0] = (double)pb[w].x;
      Bs[bk][(btx << 1) + (w << 5) + 1] = (double)pb[w].y;
    }
    __syncthreads();
    if (k0 + 16 < DDIM) {
      pa0 = *reinterpret_cast<const float4*>(Aptr + k0 + 16);
      pa1 = *reinterpret_cast<const float4*>(Aptr + k0 + 20);
#pragma unroll
      for (int w = 0; w < 4; ++w)
        pb[w] = *reinterpret_cast<const float2*>(
            Bptr + (size_t)(k0 + 16) * DDIM + (w << 5));
    }
#pragma unroll 8
    for (int kk = 0; kk < 16; ++kk) {
      double a[8];
      double2 b[4];
#pragma unroll
      for (int i = 0; i < 8; ++i) a[i] = As[(ty << 3) + i][kk];
#pragma unroll
      for (int jj = 0; jj < 4; ++jj)
        b[jj] = *reinterpret_cast<const double2*>(&Bs[kk][(tx << 1) + (jj << 5)]);
#pragma unroll
      for (int i = 0; i < 8; ++i) {
#pragma unroll
        for (int jj = 0; jj < 4; ++jj) {
          acc[i][(jj << 1) + 0] = fma(a[i], b[jj].x, acc[i][(jj << 1) + 0]);
          acc[i][(jj << 1) + 1] = fma(a[i], b[jj].y, acc[i][(jj << 1) + 1]);
        }
      }
    }
  }
#pragma unroll
  for (int i = 0; i < 8; ++i) {
    float* crow = &C[(size_t)(brow + (ty << 3) + i) * DDIM + bcol + (tx << 1)];
#pragma unroll
    for (int jj = 0; jj < 4; ++jj) {
      float2 v = make_float2((float)acc[i][(jj << 1)],
                             (float)acc[i][(jj << 1) + 1]);
      *reinterpret_cast<float2*>(crow + (jj << 5)) = v;
    }
  }
}

// ---------------------------------------------------------------------------
// k2_mfma: approx scores, 256x256 tile, 512 threads, 8 waves (2x4), NOW with
// double-buffered staging (1 barrier/K-step; regs preload step t+2 while
// staging t+1 and computing t). Epilogue unchanged (4 phases, ordered merge).
// ---------------------------------------------------------------------------
#define K2_LOAD(koff)                                                         \
  do {                                                                        \
    _Pragma("unroll")                                                         \
    for (int q = 0; q < 4; ++q) {                                             \
      const int c = (q << 9) + tid;                                           \
      const int row = c >> 3;                                                 \
      const int gs = (c & 7) ^ (row & 7);                                     \
      const float* sT = &T[(size_t)(row0g + row) * DDIM + (koff) + (gs << 3)];\
      rT[2 * q] = *reinterpret_cast<const float4*>(sT);                       \
      rT[2 * q + 1] = *reinterpret_cast<const float4*>(sT + 4);               \
      const float* sH = &H[(size_t)(col0g + row) * DDIM + (koff) + (gs << 3)];\
      rH[2 * q] = *reinterpret_cast<const float4*>(sH);                       \
      rH[2 * q + 1] = *reinterpret_cast<const float4*>(sH + 4);               \
    }                                                                         \
  } while (0)

#define K2_STAGE(bi)                                                          \
  do {                                                                        \
    _Pragma("unroll")                                                         \
    for (int q = 0; q < 4; ++q) {                                             \
      const int c = (q << 9) + tid;                                           \
      uint4 o;                                                                \
      o.x = pkbf(rT[2 * q].x, rT[2 * q].y);                                   \
      o.y = pkbf(rT[2 * q].z, rT[2 * q].w);                                   \
      o.z = pkbf(rT[2 * q + 1].x, rT[2 * q + 1].y);                           \
      o.w = pkbf(rT[2 * q + 1].z, rT[2 * q + 1].w);                           \
      *reinterpret_cast<uint4*>(&u.stage[bi][0][c << 3]) = o;                 \
      uint4 o2;                                                               \
      o2.x = pkbf(rH[2 * q].x, rH[2 * q].y);                                  \
      o2.y = pkbf(rH[2 * q].z, rH[2 * q].w);                                  \
      o2.z = pkbf(rH[2 * q + 1].x, rH[2 * q + 1].y);                          \
      o2.w = pkbf(rH[2 * q + 1].z, rH[2 * q + 1].w);                          \
      *reinterpret_cast<uint4*>(&u.stage[bi][1][c << 3]) = o2;                \
    }                                                                         \
  } while (0)

__global__ __launch_bounds__(512, 1)
void k2_mfma(const float* __restrict__ T, const float* __restrict__ H,
             unsigned short* __restrict__ cand_v,
             unsigned char* __restrict__ cand_i) {
  __shared__ union {
    unsigned short stage[2][2][256 * 64];   // 128 KB (dbuf x {T,H})
    float Sl[64][264];                      // 67.6 KB
    struct {
      float mv[512][8];
      unsigned char mi[512][8];
    } mg;
  } u;
  const int tid = threadIdx.x;
  const int lane = tid & 63;
  const int w = tid >> 6;               // 0..7
  const int wr = w >> 2, wc = w & 3;    // 2 x 4 wave grid
  const int lr = lane & 15, lg = lane >> 4;
  const int z = blockIdx.z;
  const int bx = blockIdx.x;            // col block 0..7
  const int brow = blockIdx.y << 8, bcol = bx << 8;
  const int row0g = z * SEQ + brow;
  const int col0g = z * SEQ + bcol;

  f32x4 acc[8][4];
#pragma unroll
  for (int mi = 0; mi < 8; ++mi)
#pragma unroll
    for (int nj = 0; nj < 4; ++nj)
      acc[mi][nj] = (f32x4){0.f, 0.f, 0.f, 0.f};

  float4 rT[8], rH[8];
  K2_LOAD(0);
  K2_STAGE(0);
  K2_LOAD(64);

  for (int t = 0; t < 16; ++t) {
    __syncthreads();
    const int cur = t & 1;
    if (t < 15) {
      K2_STAGE(cur ^ 1);
      if (t < 14) K2_LOAD((t + 2) << 6);
    }
#pragma unroll
    for (int kh = 0; kh < 2; ++kh) {
      const int sl = (kh << 2) + lg;
      bf16x8 bfv[4];
#pragma unroll
      for (int nj = 0; nj < 4; ++nj) {
        const int rb = (wc << 6) + (nj << 4) + lr;
        bfv[nj] = *reinterpret_cast<const bf16x8*>(
            &u.stage[cur][1][(rb << 6) + ((sl ^ (rb & 7)) << 3)]);
      }
#pragma unroll
      for (int mi = 0; mi < 8; ++mi) {
        const int ra = (wr << 7) + (mi << 4) + lr;
        const bf16x8 af = *reinterpret_cast<const bf16x8*>(
            &u.stage[cur][0][(ra << 6) + ((sl ^ (ra & 7)) << 3)]);
#pragma unroll
        for (int nj = 0; nj < 4; ++nj)
          acc[mi][nj] = __builtin_amdgcn_mfma_f32_16x16x32_bf16(
              af, bfv[nj], acc[mi][nj], 0, 0, 0);
      }
    }
  }

  // epilogue: 4 phases of 64 rows (unchanged from R9)
  const int srow = tid >> 3;     // 0..63
  const int qd = tid & 7;        // eighth (32 cols each)
#pragma unroll
  for (int p = 0; p < 4; ++p) {
    __syncthreads();
    if (wr == (p >> 1)) {
      const int mib = (p & 1) << 2;
#pragma unroll
      for (int mi2 = 0; mi2 < 4; ++mi2)
#pragma unroll
        for (int nj = 0; nj < 4; ++nj)
#pragma unroll
          for (int rg = 0; rg < 4; ++rg)
            u.Sl[(mi2 << 4) + (lg << 2) + rg][(wc << 6) + (nj << 4) + lr] =
                acc[mib + mi2][nj][rg];
    }
    __syncthreads();
    float v[KSEL];
    int ci[KSEL];
#pragma unroll
    for (int s = 0; s < KSEL; ++s) { v[s] = -3.0e38f; ci[s] = 0; }
    const int c0 = qd << 5;
    for (int c = 0; c < 32; ++c) {
      const float x = u.Sl[srow][c0 + c];
      if (x > v[KSEL - 1]) {
        float pv = x; int pc = c0 + c;
#pragma unroll
        for (int s = 0; s < KSEL; ++s) {
          if (x > v[s]) {
            const float tv = v[s]; const int tc = ci[s];
            v[s] = pv; ci[s] = pc; pv = tv; pc = tc;
          }
        }
      }
    }
    __syncthreads();   // all Sl reads done before mg overlay
#pragma unroll
    for (int s = 0; s < KSEL; ++s) {
      u.mg.mv[tid][s] = v[s];
      u.mg.mi[tid][s] = (unsigned char)ci[s];
    }
    __syncthreads();
    if (qd == 0) {
      float fv[KSEL];
      int fi[KSEL];
#pragma unroll
      for (int s = 0; s < KSEL; ++s) { fv[s] = -3.0e38f; fi[s] = 0; }
#pragma unroll
      for (int t2 = 0; t2 < 8; ++t2) {
#pragma unroll
        for (int s = 0; s < KSEL; ++s) {
          const float x = u.mg.mv[tid + t2][s];
          const int idx = u.mg.mi[tid + t2][s];
          if (x > fv[KSEL - 1]) {
            float pv = x; int pc = idx;
#pragma unroll
            for (int s2 = 0; s2 < KSEL; ++s2) {
              if (x > fv[s2]) {
                const float tv = fv[s2]; const int tc = fi[s2];
                fv[s2] = pv; fi[s2] = pc; pv = tv; pc = tc;
              }
            }
          }
        }
      }
      const size_t base =
          (size_t)(row0g + (p << 6) + srow) * 64 + ((size_t)bx << 3);
#pragma unroll
      for (int s = 0; s < KSEL; ++s) {
        cand_v[base + s] = f2bf(fv[s]);
        cand_i[base + s] = (unsigned char)fi[s];
      }
    }
  }
}

// ---------------------------------------------------------------------------
// kr_rescore: extraction (64 cands, 16 wave-max rounds) + SERIAL exact f64
// rescore + stable top-8 + weights + counts. -- UNCHANGED (R9)
// ---------------------------------------------------------------------------
__global__ __launch_bounds__(256)
void kr_rescore(const float* __restrict__ T, const float* __restrict__ H,
                const unsigned short* __restrict__ cand_v,
                const unsigned char* __restrict__ cand_i,
                int* __restrict__ topi, float* __restrict__ topw,
                int* __restrict__ cnt) {
  const int tid = threadIdx.x, lane = tid & 63, w = tid >> 6;
  const int r = blockIdx.x * 4 + w;
  const int b = r >> 11, iloc = r & (SEQ - 1);

  const size_t cbase = (size_t)r * 64;
  float v0 = bf2f(cand_v[cbase + lane]);
  int i0 = ((lane >> 3) << 8) + cand_i[cbase + lane];
  int keep = 0;
  for (int rnd = 0; rnd < 16; ++rnd) {
    float m = v0;
#pragma unroll
    for (int off = 32; off >= 1; off >>= 1) m = fmaxf(m, __shfl_xor(m, off));
    const unsigned long long bm = __ballot(v0 == m);
    const int owner = __ffsll(bm) - 1;
    const int oi = __shfl(i0, owner);
    if (lane == owner) v0 = -3.0e38f;
    if (lane == rnd) keep = oi;
  }

  const float* Trow = T + (size_t)r * DDIM;
  float4 t4[4];
#pragma unroll
  for (int q = 0; q < 4; ++q)
    t4[q] = *reinterpret_cast<const float4*>(&Trow[(q << 8) + (lane << 2)]);

  float t8v[KSEL];
  int t8i[KSEL];
#pragma unroll
  for (int p = 0; p < KSEL; ++p) { t8v[p] = -1.0f; t8i[p] = IMAXC; }

  for (int c = 0; c < 16; ++c) {
    const int j = __shfl(keep, c);
    const float* Hrow = H + ((size_t)(b << 11) + j) * DDIM;
    double s = 0.0;
#pragma unroll
    for (int q = 0; q < 4; ++q) {
      const float4 h = *reinterpret_cast<const float4*>(&Hrow[(q << 8) + (lane << 2)]);
      s = fma((double)t4[q].x, (double)h.x, s);
      s = fma((double)t4[q].y, (double)h.y, s);
      s = fma((double)t4[q].z, (double)h.z, s);
      s = fma((double)t4[q].w, (double)h.w, s);
    }
#pragma unroll
    for (int off = 1; off < 64; off <<= 1) s += __shfl_xor(s, off);
    const float aff = expf((float)s);
    const bool g7 = (aff > t8v[KSEL - 1]) ||
                    (aff == t8v[KSEL - 1] && j < t8i[KSEL - 1]);
    if (g7) {
      float pv = aff; int pi = j;
#pragma unroll
      for (int p = 0; p < KSEL; ++p) {
        const bool g = (aff > t8v[p]) || (aff == t8v[p] && j < t8i[p]);
        if (g) {
          const float tv = t8v[p]; const int ti = t8i[p];
          t8v[p] = pv; t8i[p] = pi; pv = tv; pi = ti;
        }
      }
    }
  }
  if (lane == 0) {
    float sum = 0.0f;
#pragma unroll
    for (int p = 0; p < KSEL; ++p) sum += t8v[p];
    sum += 1e-8f;
    int c8 = KSEL;
#pragma unroll
    for (int p = 0; p < KSEL; ++p)
      if (t8i[p] == iloc) --c8;
    cnt[r] = c8;
#pragma unroll
    for (int p = 0; p < KSEL; ++p) {
      topi[(size_t)r * KSEL + p] = t8i[p];
      topw[(size_t)r * KSEL + p] = t8v[p] / sum;
    }
  }
}

// ---------------------------------------------------------------------------
// k4: exclusive prefix scan of per-row counts  -- UNCHANGED
// ---------------------------------------------------------------------------
__global__ __launch_bounds__(1024)
void k4_scan(const int* __restrict__ cnt, int* __restrict__ off) {
  __shared__ int part[1024];
  const int t = threadIdx.x;
  int loc[8];
  int s = 0;
#pragma unroll
  for (int i = 0; i < 8; ++i) { loc[i] = s; s += cnt[t * 8 + i]; }
  part[t] = s;
  __syncthreads();
  for (int d = 1; d < 1024; d <<= 1) {
    const int add = (t >= d) ? part[t - d] : 0;
    __syncthreads();
    part[t] += add;
    __syncthreads();
  }
  const int base = (t == 0) ? 0 : part[t - 1];
#pragma unroll
  for (int i = 0; i < 8; ++i) off[t * 8 + i] = base + loc[i];
}

// ---------------------------------------------------------------------------
// k5: emit edges  -- UNCHANGED
// ---------------------------------------------------------------------------
__global__ __launch_bounds__(256)
void k5_emit(const int* __restrict__ topi, const float* __restrict__ topw,
             const int* __restrict__ off, float* __restrict__ out, int E) {
  const int r = blockIdx.x * 256 + threadIdx.x;
  if (r >= NROWS) return;
  const int o = off[r];
  const int sloc = r & (SEQ - 1);
  const int bbase = r & ~(SEQ - 1);
  int e = 0;
#pragma unroll
  for (int p = 0; p < KSEL; ++p) {
    const int id = topi[(size_t)r * KSEL + p];
    const float w = topw[(size_t)r * KSEL + p];
    if (id != sloc) {
      const int pos = o + e;
      if (pos < E) {
        out[pos] = (float)r;
        out[(size_t)E + pos] = (float)(bbase + id);
        out[2 * (size_t)E + pos] = w;
      }
      ++e;
    }
  }
}

// ---------------------------------------------------------------------------
extern "C" void kernel_launch(void* const* d_in, const int* in_sizes, int n_in,
                              void* d_out, int out_size, void* d_ws,
                              size_t ws_size, hipStream_t stream) {
  const float* H = (const float*)d_in[0];      // [4,2048,1024]
  const float* Wphi = (const float*)d_in[1];   // [1024,1024]
  const float* Wpsi = (const float*)d_in[2];   // [1024,1024]
  float* out = (float*)d_out;
  const int E = out_size / 3;

  char* base = (char*)d_ws;
  float* T = (float*)base;                         // 32 MB
  char* regionX = base + 33554432;                 // 4 MB shared region
  float* Wc = (float*)regionX;                     //   Wc (dead after k1)
  unsigned short* cand_v = (unsigned short*)regionX;           // 1 MB used
  unsigned char* cand_i = (unsigned char*)(regionX + 2097152); // 0.5 MB used
  char* pp = regionX + 4194304;
  int* topi = (int*)pp;  pp += 262144;
  float* topw = (float*)pp; pp += 262144;
  int* cnt = (int*)pp;   pp += 32768;
  int* off = (int*)pp;   pp += 32768;
  int* sel = (int*)pp;

  // probe f64-MFMA D layout (writes sel in-stream before any consumer)
  kprobe<<<dim3(1), 64, 0, stream>>>(sel);
  // Wc = Wphi^T * Wpsi  (f64 MFMA, dbuf; vector repair if layout unknown)
  k0_mfma<<<dim3(16, 16), 256, 0, stream>>>(Wphi, Wpsi, Wc, sel);
  k0_repair<<<dim3(16, 16), 256, 0, stream>>>(Wphi, Wpsi, Wc, sel);
  // T = H * Wc  (f64 MFMA, dbuf + setprio; vector repair if layout unknown)
  k1_mfma<<<dim3(8, 64), 256, 0, stream>>>(H, Wc, T, sel);
  k1_repair<<<dim3(8, 64), 256, 0, stream>>>(H, Wc, T, sel);
  // approx MFMA scores, 256^2 tile, dbuf staging + fused block-top-8
  k2_mfma<<<dim3(8, 8, 4), 512, 0, stream>>>(T, H, cand_v, cand_i);
  // fused extraction + exact f64 rescore + stable top-8 + weights + counts
  kr_rescore<<<dim3(NROWS / 4), 256, 0, stream>>>(T, H, cand_v, cand_i,
                                                  topi, topw, cnt);
  // prefix scan + emit
  k4_scan<<<dim3(1), 1024, 0, stream>>>(cnt, off);
  k5_emit<<<dim3(NROWS / 256), 256, 0, stream>>>(topi, topw, off, out, E);
}